// Round 6
// baseline (3814.486 us; speedup 1.0000x reference)
//
#include <hip/hip_runtime.h>

#define INCH 10
#define HID 128
#define NGRAPH 1000

__device__ __forceinline__ void atomAddF(float* p, float v) {
    unsafeAtomicAdd(p, v);   // HW global_atomic_add_f32 on gfx950
}

// ---- k0: deg = 1.0 (self-loop) ----
__global__ void k0_init_deg(float* deg, int n) {
    int i = blockIdx.x * blockDim.x + threadIdx.x;
    if (i < n) deg[i] = 1.0f;
}

// ---- k1: deg[dst] += 1 per edge ----
__global__ void k1_deg(const int* __restrict__ dst, float* deg, int e) {
    int i = blockIdx.x * blockDim.x + threadIdx.x;
    if (i < e) atomAddF(&deg[dst[i]], 1.0f);
}

// ---- k2: dinv = rsqrt(deg); a[n][:] = dinv^2 * x[n][:] (self-loop term) ----
__global__ void k2_dinv_a(const float* __restrict__ deg, const float* __restrict__ x,
                          float* __restrict__ dinv, float* __restrict__ a, int n) {
    int i = blockIdx.x * blockDim.x + threadIdx.x;
    if (i < n) {
        float r = rsqrtf(deg[i]);
        dinv[i] = r;
        float s = r * r;
        #pragma unroll
        for (int c = 0; c < INCH; c++) a[i * INCH + c] = s * x[i * INCH + c];
    }
}

// ---- k3: a[dst][:] += dinv[s]*dinv[d] * x[src][:]  (10 ch per edge) ----
__global__ void k3_edge_a(const int* __restrict__ src, const int* __restrict__ dst,
                          const float* __restrict__ dinv, const float* __restrict__ x,
                          float* __restrict__ a, int e) {
    int i = blockIdx.x * blockDim.x + threadIdx.x;
    if (i < e) {
        int s = src[i], d = dst[i];
        float w = dinv[s] * dinv[d];
        #pragma unroll
        for (int c = 0; c < INCH; c++)
            atomAddF(&a[d * INCH + c], w * x[s * INCH + c]);
    }
}

// ---- k4: h1 = relu(a @ W1 + b1); 256 thr = 2 nodes x 128 ch ----
__global__ void k4_gemm1(const float* __restrict__ a, const float* __restrict__ W1,
                         const float* __restrict__ b1, float* __restrict__ h1, int n) {
    int j = threadIdx.x & (HID - 1);
    int node = blockIdx.x * 2 + (threadIdx.x >> 7);
    if (node < n) {
        float acc = b1[j];
        #pragma unroll
        for (int c = 0; c < INCH; c++)
            acc = fmaf(a[node * INCH + c], W1[c * HID + j], acc);
        h1[node * HID + j] = fmaxf(acc, 0.0f);
    }
}

// ---- k5: u[dst][:] += dinv[src] * h1[src][:]  (32 lanes/edge, float4/lane) ----
__global__ void k5_edge_u(const int* __restrict__ src, const int* __restrict__ dst,
                          const float* __restrict__ dinv, const float* __restrict__ h1,
                          float* __restrict__ u, int e) {
    int t = blockIdx.x * blockDim.x + threadIdx.x;
    int eid = t >> 5;
    if (eid >= e) return;
    int j0 = (t & 31) * 4;
    int s = src[eid], d = dst[eid];
    float w = dinv[s];
    const float4 hv = *reinterpret_cast<const float4*>(h1 + (size_t)s * HID + j0);
    float* up = u + (size_t)d * HID + j0;
    atomAddF(up + 0, w * hv.x);
    atomAddF(up + 1, w * hv.y);
    atomAddF(up + 2, w * hv.z);
    atomAddF(up + 3, w * hv.w);
}

// ---- k6: agg2 = dinv*u + dinv^2*h1; h2 = relu(agg2 @ W2 + b2), in-place into u ----
__global__ __launch_bounds__(256, 2) void k6_gemm2(float* __restrict__ u,
                          const float* __restrict__ h1, const float* __restrict__ dinv,
                          const float* __restrict__ W2, const float* __restrict__ b2, int n) {
    __shared__ float W2s[HID * HID];      // 64 KB
    __shared__ float aggs[8 * HID];       // 4 KB
    int t = threadIdx.x;
    for (int i = t * 4; i < HID * HID; i += 256 * 4)
        *reinterpret_cast<float4*>(&W2s[i]) = *reinterpret_cast<const float4*>(&W2[i]);
    __syncthreads();

    int lane = t & 31, nl = t >> 5;
    int j0 = lane * 4;
    int ntiles = (n + 7) / 8;
    for (int tile = blockIdx.x; tile < ntiles; tile += gridDim.x) {
        int node = tile * 8 + nl;
        if (node < n) {
            float r = dinv[node];
            float s = r * r;
            float4 uv = *reinterpret_cast<float4*>(u + (size_t)node * HID + j0);
            const float4 hv = *reinterpret_cast<const float4*>(h1 + (size_t)node * HID + j0);
            aggs[nl * HID + j0 + 0] = fmaf(r, uv.x, s * hv.x);
            aggs[nl * HID + j0 + 1] = fmaf(r, uv.y, s * hv.y);
            aggs[nl * HID + j0 + 2] = fmaf(r, uv.z, s * hv.z);
            aggs[nl * HID + j0 + 3] = fmaf(r, uv.w, s * hv.w);
        }
        __syncthreads();
        if (node < n) {
            float4 acc = make_float4(b2[j0], b2[j0 + 1], b2[j0 + 2], b2[j0 + 3]);
            const float* ar = &aggs[nl * HID];
            #pragma unroll 8
            for (int k = 0; k < HID; k++) {
                float av = ar[k];
                const float4 wv = *reinterpret_cast<const float4*>(&W2s[k * HID + j0]);
                acc.x = fmaf(av, wv.x, acc.x);
                acc.y = fmaf(av, wv.y, acc.y);
                acc.z = fmaf(av, wv.z, acc.z);
                acc.w = fmaf(av, wv.w, acc.w);
            }
            float4 o = make_float4(fmaxf(acc.x, 0.f), fmaxf(acc.y, 0.f),
                                   fmaxf(acc.z, 0.f), fmaxf(acc.w, 0.f));
            *reinterpret_cast<float4*>(u + (size_t)node * HID + j0) = o;
        }
        __syncthreads();
    }
}

// ---- k7: mean-pool per graph (batch sorted -> binary search) + MLP ----
__global__ void k7_pool_mlp(const float* __restrict__ h2, const int* __restrict__ batch,
                            const float* __restrict__ Wm1, const float* __restrict__ bm1,
                            const float* __restrict__ Wm2, const float* __restrict__ bm2,
                            float* __restrict__ out, int n) {
    int g = blockIdx.x;
    int j = threadIdx.x;   // 128 threads
    // lower_bound(batch, g) and lower_bound(batch, g+1)
    int a = 0, b = n;
    while (a < b) { int m = (a + b) >> 1; if (batch[m] < g) a = m + 1; else b = m; }
    int lo = a;
    b = n;
    while (a < b) { int m = (a + b) >> 1; if (batch[m] < g + 1) a = m + 1; else b = m; }
    int hi = a;

    float sum = 0.0f;
    for (int i = lo; i < hi; i++) sum += h2[(size_t)i * HID + j];
    float cnt = (float)(hi - lo);
    float gj = sum / fmaxf(cnt, 1.0f);

    __shared__ float gl[HID];
    gl[j] = gj;
    __syncthreads();

    float acc = bm1[j];
    #pragma unroll 8
    for (int k = 0; k < HID; k++) acc = fmaf(gl[k], Wm1[k * HID + j], acc);
    float y = tanhf(acc) * Wm2[j];

    __shared__ float red[HID];
    red[j] = y;
    __syncthreads();
    if (j < 64) {
        float v = red[j] + red[j + 64];
        for (int off = 32; off; off >>= 1) v += __shfl_down(v, off);
        if (j == 0) out[g] = v + bm2[0];
    }
}

extern "C" void kernel_launch(void* const* d_in, const int* in_sizes, int n_in,
                              void* d_out, int out_size, void* d_ws, size_t ws_size,
                              hipStream_t stream) {
    const float* x    = (const float*)d_in[0];
    const int*   ei   = (const int*)d_in[1];
    const int*   batch= (const int*)d_in[2];
    // d_in[3] = num_graphs (device scalar) — fixed at 1000 by the problem
    const float* W1   = (const float*)d_in[4];
    const float* b1   = (const float*)d_in[5];
    const float* W2   = (const float*)d_in[6];
    const float* b2   = (const float*)d_in[7];
    const float* Wm1  = (const float*)d_in[8];
    const float* bm1  = (const float*)d_in[9];
    const float* Wm2  = (const float*)d_in[10];
    const float* bm2  = (const float*)d_in[11];
    float* out = (float*)d_out;

    const int N = in_sizes[0] / INCH;       // 100000
    const int E = in_sizes[1] / 2;          // 1600000
    const int G = NGRAPH;                   // 1000

    char* w = (char*)d_ws;
    float* deg  = (float*)w;                w += (size_t)N * 4;
    float* dinv = (float*)w;                w += (size_t)N * 4;
    float* a    = (float*)w;                w += (size_t)N * INCH * 4;
    float* h1   = (float*)w;                w += (size_t)N * HID * 4;
    float* u    = (float*)w;                w += (size_t)N * HID * 4;   // reused as h2

    const int* src = ei;
    const int* dst = ei + E;

    hipMemsetAsync(u, 0, (size_t)N * HID * sizeof(float), stream);

    k0_init_deg<<<(N + 255) / 256, 256, 0, stream>>>(deg, N);
    k1_deg<<<(E + 255) / 256, 256, 0, stream>>>(dst, deg, E);
    k2_dinv_a<<<(N + 255) / 256, 256, 0, stream>>>(deg, x, dinv, a, N);
    k3_edge_a<<<(E + 255) / 256, 256, 0, stream>>>(src, dst, dinv, x, a, E);
    k4_gemm1<<<(N + 1) / 2, 256, 0, stream>>>(a, W1, b1, h1, N);
    {
        long long threads = (long long)E * 32;
        int blocks = (int)((threads + 255) / 256);
        k5_edge_u<<<blocks, 256, 0, stream>>>(src, dst, dinv, h1, u, E);
    }
    k6_gemm2<<<512, 256, 0, stream>>>(u, h1, dinv, W2, b2, N);
    k7_pool_mlp<<<G, HID, 0, stream>>>(u, batch, Wm1, bm1, Wm2, bm2, out, N);
}

// Round 7
// 761.639 us; speedup vs baseline: 5.0083x; 5.0083x over previous
//
#include <hip/hip_runtime.h>

#define INCH 10
#define HID 128
#define NGRAPH 1000
#define SCAN_BLK 1024   // elements per scan block

// ======================= CSR build =======================

// hist: cnt[dst]++ per edge (int atomics, cheap, 400KB L2-resident)
__global__ void k_hist(const int* __restrict__ dst, int* __restrict__ cnt, int e) {
    int i = blockIdx.x * blockDim.x + threadIdx.x;
    if (i < e) atomicAdd(&cnt[dst[i]], 1);
}

// dinv = rsqrt(cnt + 1)   (+1 = self-loop)
__global__ void k_dinv(const int* __restrict__ cnt, float* __restrict__ dinv, int n) {
    int i = blockIdx.x * blockDim.x + threadIdx.x;
    if (i < n) dinv[i] = rsqrtf((float)(cnt[i] + 1));
}

// scan1: per-block (1024 elems) exclusive scan of cnt -> rowptr, block sums -> blk
__global__ void k_scan1(const int* __restrict__ cnt, int* __restrict__ rowptr,
                        int* __restrict__ blk, int n) {
    __shared__ int sdata[256];
    int b = blockIdx.x, t = threadIdx.x;
    int base = b * SCAN_BLK + t * 4;
    int v0 = 0, v1 = 0, v2 = 0, v3 = 0;
    if (base + 0 < n) v0 = cnt[base + 0];
    if (base + 1 < n) v1 = cnt[base + 1];
    if (base + 2 < n) v2 = cnt[base + 2];
    if (base + 3 < n) v3 = cnt[base + 3];
    int s = v0 + v1 + v2 + v3;
    sdata[t] = s;
    __syncthreads();
    for (int off = 1; off < 256; off <<= 1) {
        int x = (t >= off) ? sdata[t - off] : 0;
        __syncthreads();
        sdata[t] += x;
        __syncthreads();
    }
    int excl = sdata[t] - s;             // exclusive prefix of this thread's chunk
    if (t == 255) blk[b] = sdata[255];   // block total
    int run = excl;
    if (base + 0 < n) { rowptr[base + 0] = run; run += v0; }
    if (base + 1 < n) { rowptr[base + 1] = run; run += v1; }
    if (base + 2 < n) { rowptr[base + 2] = run; run += v2; }
    if (base + 3 < n) { rowptr[base + 3] = run; }
}

// scan2: exclusive scan of block sums (nb <= 128) in one block
__global__ void k_scan2(int* __restrict__ blk, int nb) {
    __shared__ int s[128];
    int t = threadIdx.x;
    int v = (t < nb) ? blk[t] : 0;
    s[t] = v;
    __syncthreads();
    for (int off = 1; off < 128; off <<= 1) {
        int x = (t >= off) ? s[t - off] : 0;
        __syncthreads();
        s[t] += x;
        __syncthreads();
    }
    if (t < nb) blk[t] = s[t] - v;       // exclusive
}

// scan3: rowptr += block offset; cursor = rowptr
__global__ void k_scan3(int* __restrict__ rowptr, const int* __restrict__ blk,
                        int* __restrict__ cursor, int n) {
    int i = blockIdx.x * blockDim.x + threadIdx.x;
    if (i < n) {
        int r = rowptr[i] + blk[i / SCAN_BLK];
        rowptr[i] = r;
        cursor[i] = r;
    }
}

// scatter: srclist[cursor[dst]++] = src
__global__ void k_scatter(const int* __restrict__ src, const int* __restrict__ dst,
                          int* __restrict__ cursor, int* __restrict__ srclist, int e) {
    int i = blockIdx.x * blockDim.x + threadIdx.x;
    if (i < e) {
        int p = atomicAdd(&cursor[dst[i]], 1);
        srclist[p] = src[i];
    }
}

// ======================= layer 1 =======================

// agg1: a[d][c] = dinv[d] * sum_{s in in(d)} dinv[s]*x[s][c] + dinv[d]^2 * x[d][c]
// 16 threads/node (c<10 active), 16 nodes per 256-block
__global__ void k_agg1(const int* __restrict__ rowptr, const int* __restrict__ cnt,
                       const int* __restrict__ srclist, const float* __restrict__ dinv,
                       const float* __restrict__ x, float* __restrict__ a, int n) {
    int t = blockIdx.x * blockDim.x + threadIdx.x;
    int node = t >> 4;
    int c = t & 15;
    if (node >= n || c >= INCH) return;
    int lo = rowptr[node], hi = lo + cnt[node];
    float acc = 0.0f;
    for (int e = lo; e < hi; e++) {
        int s = srclist[e];                 // broadcast across 16 lanes
        acc = fmaf(dinv[s], x[s * INCH + c], acc);
    }
    float r = dinv[node];
    a[node * INCH + c] = r * fmaf(r, x[node * INCH + c], acc);
}

// k4: h1 = relu(a @ W1 + b1); 256 thr = 2 nodes x 128 ch
__global__ void k4_gemm1(const float* __restrict__ a, const float* __restrict__ W1,
                         const float* __restrict__ b1, float* __restrict__ h1, int n) {
    int j = threadIdx.x & (HID - 1);
    int node = blockIdx.x * 2 + (threadIdx.x >> 7);
    if (node < n) {
        float acc = b1[j];
        #pragma unroll
        for (int c = 0; c < INCH; c++)
            acc = fmaf(a[node * INCH + c], W1[c * HID + j], acc);
        h1[node * HID + j] = fmaxf(acc, 0.0f);
    }
}

// ======================= layer 2 (fused agg + GEMM) =======================
// per node: agg[j] = dinv[d]*sum dinv[s]*h1[s][j] + dinv[d]^2*h1[d][j]
// then u[d][:] = relu(agg @ W2 + b2). 8 nodes/block-tile, 32 lanes x float4 each.
__global__ __launch_bounds__(256, 2) void k_agg2gemm2(
        const int* __restrict__ rowptr, const int* __restrict__ cnt,
        const int* __restrict__ srclist, const float* __restrict__ dinv,
        const float* __restrict__ h1, const float* __restrict__ W2,
        const float* __restrict__ b2, float* __restrict__ u, int n) {
    __shared__ float W2s[HID * HID];      // 64 KB
    __shared__ float aggs[8 * HID];       // 4 KB
    int t = threadIdx.x;
    for (int i = t * 4; i < HID * HID; i += 256 * 4)
        *reinterpret_cast<float4*>(&W2s[i]) = *reinterpret_cast<const float4*>(&W2[i]);
    __syncthreads();

    int lane = t & 31, nl = t >> 5;
    int j0 = lane * 4;
    int ntiles = (n + 7) / 8;
    for (int tile = blockIdx.x; tile < ntiles; tile += gridDim.x) {
        int node = tile * 8 + nl;
        if (node < n) {
            int lo = rowptr[node], hi = lo + cnt[node];
            float4 acc = make_float4(0.f, 0.f, 0.f, 0.f);
            for (int e = lo; e < hi; e++) {
                int s = srclist[e];          // broadcast across the 32 lanes
                float w = dinv[s];
                const float4 hv = *reinterpret_cast<const float4*>(h1 + (size_t)s * HID + j0);
                acc.x = fmaf(w, hv.x, acc.x);
                acc.y = fmaf(w, hv.y, acc.y);
                acc.z = fmaf(w, hv.z, acc.z);
                acc.w = fmaf(w, hv.w, acc.w);
            }
            float r = dinv[node];
            const float4 hs = *reinterpret_cast<const float4*>(h1 + (size_t)node * HID + j0);
            aggs[nl * HID + j0 + 0] = r * fmaf(r, hs.x, acc.x);
            aggs[nl * HID + j0 + 1] = r * fmaf(r, hs.y, acc.y);
            aggs[nl * HID + j0 + 2] = r * fmaf(r, hs.z, acc.z);
            aggs[nl * HID + j0 + 3] = r * fmaf(r, hs.w, acc.w);
        }
        __syncthreads();
        if (node < n) {
            float4 acc = make_float4(b2[j0], b2[j0 + 1], b2[j0 + 2], b2[j0 + 3]);
            const float* ar = &aggs[nl * HID];
            #pragma unroll 8
            for (int k = 0; k < HID; k++) {
                float av = ar[k];
                const float4 wv = *reinterpret_cast<const float4*>(&W2s[k * HID + j0]);
                acc.x = fmaf(av, wv.x, acc.x);
                acc.y = fmaf(av, wv.y, acc.y);
                acc.z = fmaf(av, wv.z, acc.z);
                acc.w = fmaf(av, wv.w, acc.w);
            }
            float4 o = make_float4(fmaxf(acc.x, 0.f), fmaxf(acc.y, 0.f),
                                   fmaxf(acc.z, 0.f), fmaxf(acc.w, 0.f));
            *reinterpret_cast<float4*>(u + (size_t)node * HID + j0) = o;
        }
        __syncthreads();
    }
}

// ======================= pool + MLP =======================
__global__ void k7_pool_mlp(const float* __restrict__ h2, const int* __restrict__ batch,
                            const float* __restrict__ Wm1, const float* __restrict__ bm1,
                            const float* __restrict__ Wm2, const float* __restrict__ bm2,
                            float* __restrict__ out, int n) {
    int g = blockIdx.x;
    int j = threadIdx.x;   // 128 threads
    int a = 0, b = n;
    while (a < b) { int m = (a + b) >> 1; if (batch[m] < g) a = m + 1; else b = m; }
    int lo = a;
    b = n;
    while (a < b) { int m = (a + b) >> 1; if (batch[m] < g + 1) a = m + 1; else b = m; }
    int hi = a;

    float sum = 0.0f;
    for (int i = lo; i < hi; i++) sum += h2[(size_t)i * HID + j];
    float cnt = (float)(hi - lo);
    float gj = sum / fmaxf(cnt, 1.0f);

    __shared__ float gl[HID];
    gl[j] = gj;
    __syncthreads();

    float acc = bm1[j];
    #pragma unroll 8
    for (int k = 0; k < HID; k++) acc = fmaf(gl[k], Wm1[k * HID + j], acc);
    float y = tanhf(acc) * Wm2[j];

    __shared__ float red[HID];
    red[j] = y;
    __syncthreads();
    if (j < 64) {
        float v = red[j] + red[j + 64];
        for (int off = 32; off; off >>= 1) v += __shfl_down(v, off);
        if (j == 0) out[g] = v + bm2[0];
    }
}

extern "C" void kernel_launch(void* const* d_in, const int* in_sizes, int n_in,
                              void* d_out, int out_size, void* d_ws, size_t ws_size,
                              hipStream_t stream) {
    const float* x    = (const float*)d_in[0];
    const int*   ei   = (const int*)d_in[1];
    const int*   batch= (const int*)d_in[2];
    const float* W1   = (const float*)d_in[4];
    const float* b1   = (const float*)d_in[5];
    const float* W2   = (const float*)d_in[6];
    const float* b2   = (const float*)d_in[7];
    const float* Wm1  = (const float*)d_in[8];
    const float* bm1  = (const float*)d_in[9];
    const float* Wm2  = (const float*)d_in[10];
    const float* bm2  = (const float*)d_in[11];
    float* out = (float*)d_out;

    const int N = in_sizes[0] / INCH;       // 100000
    const int E = in_sizes[1] / 2;          // 1600000
    const int G = NGRAPH;                   // 1000
    const int NB = (N + SCAN_BLK - 1) / SCAN_BLK;   // 98 (<=128 required by k_scan2)

    char* w = (char*)d_ws;
    int*   cnt     = (int*)w;     w += (size_t)N * 4;
    int*   rowptr  = (int*)w;     w += (size_t)N * 4;
    int*   cursor  = (int*)w;     w += (size_t)N * 4;
    int*   blk     = (int*)w;     w += 256 * 4;
    float* dinv    = (float*)w;   w += (size_t)N * 4;
    int*   srclist = (int*)w;     w += (size_t)E * 4;
    float* a       = (float*)w;   w += (size_t)N * INCH * 4;
    float* h1      = (float*)w;   w += (size_t)N * HID * 4;
    float* u       = (float*)w;   w += (size_t)N * HID * 4;   // h2 output

    const int* src = ei;
    const int* dst = ei + E;

    hipMemsetAsync(cnt, 0, (size_t)N * sizeof(int), stream);

    k_hist   <<<(E + 255) / 256, 256, 0, stream>>>(dst, cnt, E);
    k_dinv   <<<(N + 255) / 256, 256, 0, stream>>>(cnt, dinv, N);
    k_scan1  <<<NB, 256, 0, stream>>>(cnt, rowptr, blk, N);
    k_scan2  <<<1, 128, 0, stream>>>(blk, NB);
    k_scan3  <<<(N + 255) / 256, 256, 0, stream>>>(rowptr, blk, cursor, N);
    k_scatter<<<(E + 255) / 256, 256, 0, stream>>>(src, dst, cursor, srclist, E);

    k_agg1   <<<(N * 16 + 255) / 256, 256, 0, stream>>>(rowptr, cnt, srclist, dinv, x, a, N);
    k4_gemm1 <<<(N + 1) / 2, 256, 0, stream>>>(a, W1, b1, h1, N);

    k_agg2gemm2<<<512, 256, 0, stream>>>(rowptr, cnt, srclist, dinv, h1, W2, b2, u, N);

    k7_pool_mlp<<<G, HID, 0, stream>>>(u, batch, Wm1, bm1, Wm2, bm2, out, N);
}

// Round 9
// 600.662 us; speedup vs baseline: 6.3505x; 1.2680x over previous
//
#include <hip/hip_runtime.h>

#define INCH 10
#define HID 128
#define NGRAPH 1000
#define SCAN_BLK 1024   // elements per scan block

// ======================= CSR build =======================

__global__ void k_hist(const int* __restrict__ dst, int* __restrict__ cnt, int e) {
    int i = blockIdx.x * blockDim.x + threadIdx.x;
    if (i < e) atomicAdd(&cnt[dst[i]], 1);
}

__global__ void k_dinv(const int* __restrict__ cnt, float* __restrict__ dinv, int n) {
    int i = blockIdx.x * blockDim.x + threadIdx.x;
    if (i < n) dinv[i] = rsqrtf((float)(cnt[i] + 1));
}

__global__ void k_scan1(const int* __restrict__ cnt, int* __restrict__ rowptr,
                        int* __restrict__ blk, int n) {
    __shared__ int sdata[256];
    int b = blockIdx.x, t = threadIdx.x;
    int base = b * SCAN_BLK + t * 4;
    int v0 = 0, v1 = 0, v2 = 0, v3 = 0;
    if (base + 0 < n) v0 = cnt[base + 0];
    if (base + 1 < n) v1 = cnt[base + 1];
    if (base + 2 < n) v2 = cnt[base + 2];
    if (base + 3 < n) v3 = cnt[base + 3];
    int s = v0 + v1 + v2 + v3;
    sdata[t] = s;
    __syncthreads();
    for (int off = 1; off < 256; off <<= 1) {
        int x = (t >= off) ? sdata[t - off] : 0;
        __syncthreads();
        sdata[t] += x;
        __syncthreads();
    }
    int excl = sdata[t] - s;
    if (t == 255) blk[b] = sdata[255];
    int run = excl;
    if (base + 0 < n) { rowptr[base + 0] = run; run += v0; }
    if (base + 1 < n) { rowptr[base + 1] = run; run += v1; }
    if (base + 2 < n) { rowptr[base + 2] = run; run += v2; }
    if (base + 3 < n) { rowptr[base + 3] = run; }
}

__global__ void k_scan2(int* __restrict__ blk, int nb) {
    __shared__ int s[128];
    int t = threadIdx.x;
    int v = (t < nb) ? blk[t] : 0;
    s[t] = v;
    __syncthreads();
    for (int off = 1; off < 128; off <<= 1) {
        int x = (t >= off) ? s[t - off] : 0;
        __syncthreads();
        s[t] += x;
        __syncthreads();
    }
    if (t < nb) blk[t] = s[t] - v;
}

__global__ void k_scan3(int* __restrict__ rowptr, const int* __restrict__ blk,
                        int* __restrict__ cursor, int n) {
    int i = blockIdx.x * blockDim.x + threadIdx.x;
    if (i < n) {
        int r = rowptr[i] + blk[i / SCAN_BLK];
        rowptr[i] = r;
        cursor[i] = r;
    }
}

__global__ void k_scatter(const int* __restrict__ src, const int* __restrict__ dst,
                          int* __restrict__ cursor, int* __restrict__ srclist, int e) {
    int i = blockIdx.x * blockDim.x + threadIdx.x;
    if (i < e) {
        int p = atomicAdd(&cursor[dst[i]], 1);
        srclist[p] = src[i];
    }
}

// ======================= layer 1 fused: agg (edge-parallel) + GEMM1 =======================
// wave = 2 nodes (32 lanes each). Lanes gather different edges in parallel (x is
// L2-resident, 10 scalar loads each, huge memory-level parallelism),
// butterfly-reduce 10 channels, then in-register 10x128 GEMM.
__global__ __launch_bounds__(256) void k_l1fused(
        const int* __restrict__ rowptr, const int* __restrict__ cnt,
        const int* __restrict__ srclist, const float* __restrict__ dinv,
        const float* __restrict__ x, const float* __restrict__ W1,
        const float* __restrict__ b1, float* __restrict__ h1, int n) {
    int t = blockIdx.x * blockDim.x + threadIdx.x;
    int node = t >> 5;              // 32 lanes per node
    int l32 = t & 31;
    if (node >= n) return;

    int lo = rowptr[node], deg = cnt[node];
    float acc[INCH];
    #pragma unroll
    for (int c = 0; c < INCH; c++) acc[c] = 0.0f;

    for (int e = lo + l32; e < lo + deg; e += 32) {
        int s = srclist[e];
        float w = dinv[s];
        #pragma unroll
        for (int c = 0; c < INCH; c++)
            acc[c] = fmaf(w, x[s * INCH + c], acc[c]);
    }
    // butterfly reduce within the 32-lane group
    #pragma unroll
    for (int m = 16; m; m >>= 1) {
        #pragma unroll
        for (int c = 0; c < INCH; c++)
            acc[c] += __shfl_xor(acc[c], m, 32);
    }
    // self-loop + outer norm: agg[c] = r*(acc[c] + r*x[node][c])
    float r = dinv[node];
    float agg[INCH];
    #pragma unroll
    for (int c = 0; c < INCH; c++)
        agg[c] = r * fmaf(r, x[node * INCH + c], acc[c]);

    // GEMM1: each lane computes 4 output channels
    int j0 = l32 * 4;
    float4 o = *reinterpret_cast<const float4*>(b1 + j0);
    #pragma unroll
    for (int c = 0; c < INCH; c++) {
        const float4 wv = *reinterpret_cast<const float4*>(W1 + c * HID + j0);
        o.x = fmaf(agg[c], wv.x, o.x);
        o.y = fmaf(agg[c], wv.y, o.y);
        o.z = fmaf(agg[c], wv.z, o.z);
        o.w = fmaf(agg[c], wv.w, o.w);
    }
    float4 res = make_float4(fmaxf(o.x, 0.f), fmaxf(o.y, 0.f),
                             fmaxf(o.z, 0.f), fmaxf(o.w, 0.f));
    *reinterpret_cast<float4*>(h1 + (size_t)node * HID + j0) = res;
}

// ======================= layer 2 fused: agg + GEMM2 =======================
// 8 nodes/block, 32 lanes x float4 each. No W2 LDS staging (global reads L1-hit,
// shared by the 8 node-groups) -> LDS 4KB -> high occupancy. 2-way unrolled gather.
__global__ __launch_bounds__(256) void k_agg2gemm2(
        const int* __restrict__ rowptr, const int* __restrict__ cnt,
        const int* __restrict__ srclist, const float* __restrict__ dinv,
        const float* __restrict__ h1, const float* __restrict__ W2,
        const float* __restrict__ b2, float* __restrict__ u, int n) {
    __shared__ float aggs[8 * HID];       // 4 KB
    int t = threadIdx.x;
    int nl = t >> 5, l32 = t & 31;
    int j0 = l32 * 4;
    int node = blockIdx.x * 8 + nl;

    if (node < n) {
        int lo = rowptr[node], hi = lo + cnt[node];
        float4 acc = make_float4(0.f, 0.f, 0.f, 0.f);
        int e = lo;
        for (; e + 2 <= hi; e += 2) {           // two independent gather chains
            int s0 = srclist[e], s1 = srclist[e + 1];
            float w0 = dinv[s0], w1 = dinv[s1];
            const float4 a0 = *reinterpret_cast<const float4*>(h1 + (size_t)s0 * HID + j0);
            const float4 a1 = *reinterpret_cast<const float4*>(h1 + (size_t)s1 * HID + j0);
            acc.x = fmaf(w0, a0.x, acc.x); acc.y = fmaf(w0, a0.y, acc.y);
            acc.z = fmaf(w0, a0.z, acc.z); acc.w = fmaf(w0, a0.w, acc.w);
            acc.x = fmaf(w1, a1.x, acc.x); acc.y = fmaf(w1, a1.y, acc.y);
            acc.z = fmaf(w1, a1.z, acc.z); acc.w = fmaf(w1, a1.w, acc.w);
        }
        if (e < hi) {
            int s0 = srclist[e];
            float w0 = dinv[s0];
            const float4 a0 = *reinterpret_cast<const float4*>(h1 + (size_t)s0 * HID + j0);
            acc.x = fmaf(w0, a0.x, acc.x); acc.y = fmaf(w0, a0.y, acc.y);
            acc.z = fmaf(w0, a0.z, acc.z); acc.w = fmaf(w0, a0.w, acc.w);
        }
        float r = dinv[node];
        const float4 hs = *reinterpret_cast<const float4*>(h1 + (size_t)node * HID + j0);
        aggs[nl * HID + j0 + 0] = r * fmaf(r, hs.x, acc.x);
        aggs[nl * HID + j0 + 1] = r * fmaf(r, hs.y, acc.y);
        aggs[nl * HID + j0 + 2] = r * fmaf(r, hs.z, acc.z);
        aggs[nl * HID + j0 + 3] = r * fmaf(r, hs.w, acc.w);
    }
    __syncthreads();
    if (node < n) {
        float4 o = *reinterpret_cast<const float4*>(b2 + j0);
        const float* ar = &aggs[nl * HID];
        #pragma unroll 8
        for (int k = 0; k < HID; k++) {
            float av = ar[k];                                   // LDS broadcast
            const float4 wv = *reinterpret_cast<const float4*>(W2 + k * HID + j0);  // L1-hit
            o.x = fmaf(av, wv.x, o.x);
            o.y = fmaf(av, wv.y, o.y);
            o.z = fmaf(av, wv.z, o.z);
            o.w = fmaf(av, wv.w, o.w);
        }
        float4 res = make_float4(fmaxf(o.x, 0.f), fmaxf(o.y, 0.f),
                                 fmaxf(o.z, 0.f), fmaxf(o.w, 0.f));
        *reinterpret_cast<float4*>(u + (size_t)node * HID + j0) = res;
    }
}

// ======================= pool + MLP =======================
__global__ void k7_pool_mlp(const float* __restrict__ h2, const int* __restrict__ batch,
                            const float* __restrict__ Wm1, const float* __restrict__ bm1,
                            const float* __restrict__ Wm2, const float* __restrict__ bm2,
                            float* __restrict__ out, int n) {
    int g = blockIdx.x;
    int j = threadIdx.x;   // 128 threads
    int a = 0, b = n;
    while (a < b) { int m = (a + b) >> 1; if (batch[m] < g) a = m + 1; else b = m; }
    int lo = a;
    b = n;
    while (a < b) { int m = (a + b) >> 1; if (batch[m] < g + 1) a = m + 1; else b = m; }
    int hi = a;

    float sum = 0.0f;
    for (int i = lo; i < hi; i++) sum += h2[(size_t)i * HID + j];
    float cnt = (float)(hi - lo);
    float gj = sum / fmaxf(cnt, 1.0f);

    __shared__ float gl[HID];
    gl[j] = gj;
    __syncthreads();

    float acc = bm1[j];
    #pragma unroll 8
    for (int k = 0; k < HID; k++) acc = fmaf(gl[k], Wm1[k * HID + j], acc);
    float y = tanhf(acc) * Wm2[j];

    __shared__ float red[HID];
    red[j] = y;
    __syncthreads();
    if (j < 64) {
        float v = red[j] + red[j + 64];
        for (int off = 32; off; off >>= 1) v += __shfl_down(v, off);
        if (j == 0) out[g] = v + bm2[0];
    }
}

extern "C" void kernel_launch(void* const* d_in, const int* in_sizes, int n_in,
                              void* d_out, int out_size, void* d_ws, size_t ws_size,
                              hipStream_t stream) {
    const float* x    = (const float*)d_in[0];
    const int*   ei   = (const int*)d_in[1];
    const int*   batch= (const int*)d_in[2];
    const float* W1   = (const float*)d_in[4];
    const float* b1   = (const float*)d_in[5];
    const float* W2   = (const float*)d_in[6];
    const float* b2   = (const float*)d_in[7];
    const float* Wm1  = (const float*)d_in[8];
    const float* bm1  = (const float*)d_in[9];
    const float* Wm2  = (const float*)d_in[10];
    const float* bm2  = (const float*)d_in[11];
    float* out = (float*)d_out;

    const int N = in_sizes[0] / INCH;       // 100000
    const int E = in_sizes[1] / 2;          // 1600000
    const int G = NGRAPH;                   // 1000
    const int NB = (N + SCAN_BLK - 1) / SCAN_BLK;   // 98 (<=128 required by k_scan2)

    char* w = (char*)d_ws;
    int*   cnt     = (int*)w;     w += (size_t)N * 4;
    int*   rowptr  = (int*)w;     w += (size_t)N * 4;
    int*   cursor  = (int*)w;     w += (size_t)N * 4;
    int*   blk     = (int*)w;     w += 256 * 4;
    float* dinv    = (float*)w;   w += (size_t)N * 4;
    int*   srclist = (int*)w;     w += (size_t)E * 4;
    float* h1      = (float*)w;   w += (size_t)N * HID * 4;
    float* u       = (float*)w;   w += (size_t)N * HID * 4;   // h2 output

    const int* src = ei;
    const int* dst = ei + E;

    hipMemsetAsync(cnt, 0, (size_t)N * sizeof(int), stream);

    k_hist   <<<(E + 255) / 256, 256, 0, stream>>>(dst, cnt, E);
    k_dinv   <<<(N + 255) / 256, 256, 0, stream>>>(cnt, dinv, N);
    k_scan1  <<<NB, 256, 0, stream>>>(cnt, rowptr, blk, N);
    k_scan2  <<<1, 128, 0, stream>>>(blk, NB);
    k_scan3  <<<(N + 255) / 256, 256, 0, stream>>>(rowptr, blk, cursor, N);
    k_scatter<<<(E + 255) / 256, 256, 0, stream>>>(src, dst, cursor, srclist, E);

    k_l1fused<<<(N * 32 + 255) / 256, 256, 0, stream>>>(rowptr, cnt, srclist, dinv,
                                                        x, W1, b1, h1, N);
    k_agg2gemm2<<<(N + 7) / 8, 256, 0, stream>>>(rowptr, cnt, srclist, dinv,
                                                 h1, W2, b2, u, N);
    k7_pool_mlp<<<G, HID, 0, stream>>>(u, batch, Wm1, bm1, Wm2, bm2, out, N);
}

// Round 11
// 591.782 us; speedup vs baseline: 6.4458x; 1.0150x over previous
//
#include <hip/hip_runtime.h>

#define INCH 10
#define HID 128
#define NGRAPH 1000
#define SCAN_BLK 1024   // elements per scan block

// ======================= CSR build =======================

__global__ void k_hist(const int* __restrict__ dst, int* __restrict__ cnt, int e) {
    int i = blockIdx.x * blockDim.x + threadIdx.x;
    if (i < e) atomicAdd(&cnt[dst[i]], 1);
}

__global__ void k_scan1(const int* __restrict__ cnt, int* __restrict__ rowptr,
                        int* __restrict__ blk, int n) {
    __shared__ int sdata[256];
    int b = blockIdx.x, t = threadIdx.x;
    int base = b * SCAN_BLK + t * 4;
    int v0 = 0, v1 = 0, v2 = 0, v3 = 0;
    if (base + 0 < n) v0 = cnt[base + 0];
    if (base + 1 < n) v1 = cnt[base + 1];
    if (base + 2 < n) v2 = cnt[base + 2];
    if (base + 3 < n) v3 = cnt[base + 3];
    int s = v0 + v1 + v2 + v3;
    sdata[t] = s;
    __syncthreads();
    for (int off = 1; off < 256; off <<= 1) {
        int x = (t >= off) ? sdata[t - off] : 0;
        __syncthreads();
        sdata[t] += x;
        __syncthreads();
    }
    int excl = sdata[t] - s;
    if (t == 255) blk[b] = sdata[255];
    int run = excl;
    if (base + 0 < n) { rowptr[base + 0] = run; run += v0; }
    if (base + 1 < n) { rowptr[base + 1] = run; run += v1; }
    if (base + 2 < n) { rowptr[base + 2] = run; run += v2; }
    if (base + 3 < n) { rowptr[base + 3] = run; }
}

__global__ void k_scan2(int* __restrict__ blk, int nb) {
    __shared__ int s[128];
    int t = threadIdx.x;
    int v = (t < nb) ? blk[t] : 0;
    s[t] = v;
    __syncthreads();
    for (int off = 1; off < 128; off <<= 1) {
        int x = (t >= off) ? s[t - off] : 0;
        __syncthreads();
        s[t] += x;
        __syncthreads();
    }
    if (t < nb) blk[t] = s[t] - v;
}

// scan3 + dinv + xs = dinv*x  (fused epilogue of CSR build)
__global__ void k_scan3(int* __restrict__ rowptr, const int* __restrict__ blk,
                        int* __restrict__ cursor, const int* __restrict__ cnt,
                        float* __restrict__ dinv, const float* __restrict__ x,
                        float* __restrict__ xs, int n) {
    int i = blockIdx.x * blockDim.x + threadIdx.x;
    if (i < n) {
        int r = rowptr[i] + blk[i / SCAN_BLK];
        rowptr[i] = r;
        cursor[i] = r;
        float rv = rsqrtf((float)(cnt[i] + 1));
        dinv[i] = rv;
        #pragma unroll
        for (int c = 0; c < INCH; c++)
            xs[i * INCH + c] = rv * x[i * INCH + c];
    }
}

__global__ void k_scatter(const int* __restrict__ src, const int* __restrict__ dst,
                          int* __restrict__ cursor, int* __restrict__ srclist, int e) {
    int i = blockIdx.x * blockDim.x + threadIdx.x;
    if (i < e) {
        int p = atomicAdd(&cursor[dst[i]], 1);
        srclist[p] = src[i];
    }
}

// ======================= layer 1 fused: agg + GEMM1, outputs h1' = dinv*relu(...) ====
// wave-half = 1 node (32 lanes). Lanes own different edges; chain is srclist->xs only.
__global__ __launch_bounds__(256) void k_l1fused(
        const int* __restrict__ rowptr, const int* __restrict__ cnt,
        const int* __restrict__ srclist, const float* __restrict__ dinv,
        const float* __restrict__ xs, const float* __restrict__ W1,
        const float* __restrict__ b1, float* __restrict__ h1, int n) {
    int t = blockIdx.x * blockDim.x + threadIdx.x;
    int node = t >> 5;              // 32 lanes per node
    int l32 = t & 31;
    if (node >= n) return;

    int lo = rowptr[node], deg = cnt[node];
    float acc[INCH];
    #pragma unroll
    for (int c = 0; c < INCH; c++) acc[c] = 0.0f;

    for (int e = lo + l32; e < lo + deg; e += 32) {
        int s = srclist[e];
        #pragma unroll
        for (int c = 0; c < INCH; c++)
            acc[c] += xs[s * INCH + c];          // xs already dinv-scaled
    }
    #pragma unroll
    for (int m = 16; m; m >>= 1) {
        #pragma unroll
        for (int c = 0; c < INCH; c++)
            acc[c] += __shfl_xor(acc[c], m, 32);
    }
    // agg[c] = r*(sum + xs[node][c])
    float r = dinv[node];
    float agg[INCH];
    #pragma unroll
    for (int c = 0; c < INCH; c++)
        agg[c] = r * (acc[c] + xs[node * INCH + c]);

    // GEMM1: each lane computes 4 output channels; store h1' = r*relu(.)
    int j0 = l32 * 4;
    float4 o = *reinterpret_cast<const float4*>(b1 + j0);
    #pragma unroll
    for (int c = 0; c < INCH; c++) {
        const float4 wv = *reinterpret_cast<const float4*>(W1 + c * HID + j0);
        o.x = fmaf(agg[c], wv.x, o.x);
        o.y = fmaf(agg[c], wv.y, o.y);
        o.z = fmaf(agg[c], wv.z, o.z);
        o.w = fmaf(agg[c], wv.w, o.w);
    }
    float4 res = make_float4(r * fmaxf(o.x, 0.f), r * fmaxf(o.y, 0.f),
                             r * fmaxf(o.z, 0.f), r * fmaxf(o.w, 0.f));
    *reinterpret_cast<float4*>(h1 + (size_t)node * HID + j0) = res;
}

// ======================= layer 2 fused: agg + GEMM2 =======================
// h1 is pre-scaled (h1' = dinv*relu); agg2 = r*(sum h1'[s] + h1'[d]).
// 8 nodes/block, 32 lanes x float4. 4-deep unrolled gather (4 chains in flight).
__global__ __launch_bounds__(256) void k_agg2gemm2(
        const int* __restrict__ rowptr, const int* __restrict__ cnt,
        const int* __restrict__ srclist, const float* __restrict__ dinv,
        const float* __restrict__ h1, const float* __restrict__ W2,
        const float* __restrict__ b2, float* __restrict__ u, int n) {
    __shared__ float aggs[8 * HID];       // 4 KB
    int t = threadIdx.x;
    int nl = t >> 5, l32 = t & 31;
    int j0 = l32 * 4;
    int node = blockIdx.x * 8 + nl;

    if (node < n) {
        int lo = rowptr[node], hi = lo + cnt[node];
        float4 acc = make_float4(0.f, 0.f, 0.f, 0.f);
        int e = lo;
        for (; e + 4 <= hi; e += 4) {           // four independent gather chains
            int s0 = srclist[e], s1 = srclist[e + 1];
            int s2 = srclist[e + 2], s3 = srclist[e + 3];
            const float4 a0 = *reinterpret_cast<const float4*>(h1 + (size_t)s0 * HID + j0);
            const float4 a1 = *reinterpret_cast<const float4*>(h1 + (size_t)s1 * HID + j0);
            const float4 a2 = *reinterpret_cast<const float4*>(h1 + (size_t)s2 * HID + j0);
            const float4 a3 = *reinterpret_cast<const float4*>(h1 + (size_t)s3 * HID + j0);
            acc.x += a0.x + a1.x + a2.x + a3.x;
            acc.y += a0.y + a1.y + a2.y + a3.y;
            acc.z += a0.z + a1.z + a2.z + a3.z;
            acc.w += a0.w + a1.w + a2.w + a3.w;
        }
        for (; e < hi; e++) {
            int s0 = srclist[e];
            const float4 a0 = *reinterpret_cast<const float4*>(h1 + (size_t)s0 * HID + j0);
            acc.x += a0.x; acc.y += a0.y; acc.z += a0.z; acc.w += a0.w;
        }
        float r = dinv[node];
        const float4 hs = *reinterpret_cast<const float4*>(h1 + (size_t)node * HID + j0);
        aggs[nl * HID + j0 + 0] = r * (acc.x + hs.x);
        aggs[nl * HID + j0 + 1] = r * (acc.y + hs.y);
        aggs[nl * HID + j0 + 2] = r * (acc.z + hs.z);
        aggs[nl * HID + j0 + 3] = r * (acc.w + hs.w);
    }
    __syncthreads();
    if (node < n) {
        float4 o = *reinterpret_cast<const float4*>(b2 + j0);
        const float* ar = &aggs[nl * HID];
        #pragma unroll 8
        for (int k = 0; k < HID; k++) {
            float av = ar[k];                                   // LDS broadcast
            const float4 wv = *reinterpret_cast<const float4*>(W2 + k * HID + j0);  // L1-hit
            o.x = fmaf(av, wv.x, o.x);
            o.y = fmaf(av, wv.y, o.y);
            o.z = fmaf(av, wv.z, o.z);
            o.w = fmaf(av, wv.w, o.w);
        }
        float4 res = make_float4(fmaxf(o.x, 0.f), fmaxf(o.y, 0.f),
                                 fmaxf(o.z, 0.f), fmaxf(o.w, 0.f));
        *reinterpret_cast<float4*>(u + (size_t)node * HID + j0) = res;
    }
}

// ======================= pool + MLP =======================
__global__ void k7_pool_mlp(const float* __restrict__ h2, const int* __restrict__ batch,
                            const float* __restrict__ Wm1, const float* __restrict__ bm1,
                            const float* __restrict__ Wm2, const float* __restrict__ bm2,
                            float* __restrict__ out, int n) {
    int g = blockIdx.x;
    int j = threadIdx.x;   // 128 threads
    int a = 0, b = n;
    while (a < b) { int m = (a + b) >> 1; if (batch[m] < g) a = m + 1; else b = m; }
    int lo = a;
    b = n;
    while (a < b) { int m = (a + b) >> 1; if (batch[m] < g + 1) a = m + 1; else b = m; }
    int hi = a;

    float sum = 0.0f;
    for (int i = lo; i < hi; i++) sum += h2[(size_t)i * HID + j];
    float cnt = (float)(hi - lo);
    float gj = sum / fmaxf(cnt, 1.0f);

    __shared__ float gl[HID];
    gl[j] = gj;
    __syncthreads();

    float acc = bm1[j];
    #pragma unroll 8
    for (int k = 0; k < HID; k++) acc = fmaf(gl[k], Wm1[k * HID + j], acc);
    float y = tanhf(acc) * Wm2[j];

    __shared__ float red[HID];
    red[j] = y;
    __syncthreads();
    if (j < 64) {
        float v = red[j] + red[j + 64];
        for (int off = 32; off; off >>= 1) v += __shfl_down(v, off);
        if (j == 0) out[g] = v + bm2[0];
    }
}

extern "C" void kernel_launch(void* const* d_in, const int* in_sizes, int n_in,
                              void* d_out, int out_size, void* d_ws, size_t ws_size,
                              hipStream_t stream) {
    const float* x    = (const float*)d_in[0];
    const int*   ei   = (const int*)d_in[1];
    const int*   batch= (const int*)d_in[2];
    const float* W1   = (const float*)d_in[4];
    const float* b1   = (const float*)d_in[5];
    const float* W2   = (const float*)d_in[6];
    const float* b2   = (const float*)d_in[7];
    const float* Wm1  = (const float*)d_in[8];
    const float* bm1  = (const float*)d_in[9];
    const float* Wm2  = (const float*)d_in[10];
    const float* bm2  = (const float*)d_in[11];
    float* out = (float*)d_out;

    const int N = in_sizes[0] / INCH;       // 100000
    const int E = in_sizes[1] / 2;          // 1600000
    const int G = NGRAPH;                   // 1000
    const int NB = (N + SCAN_BLK - 1) / SCAN_BLK;   // 98 (<=128 required by k_scan2)

    char* w = (char*)d_ws;
    int*   cnt     = (int*)w;     w += (size_t)N * 4;
    int*   rowptr  = (int*)w;     w += (size_t)N * 4;
    int*   cursor  = (int*)w;     w += (size_t)N * 4;
    int*   blk     = (int*)w;     w += 256 * 4;
    float* dinv    = (float*)w;   w += (size_t)N * 4;
    float* xs      = (float*)w;   w += (size_t)N * INCH * 4;
    int*   srclist = (int*)w;     w += (size_t)E * 4;
    float* h1      = (float*)w;   w += (size_t)N * HID * 4;   // h1' = dinv*relu(...)
    float* u       = (float*)w;   w += (size_t)N * HID * 4;   // h2 output

    const int* src = ei;
    const int* dst = ei + E;

    hipMemsetAsync(cnt, 0, (size_t)N * sizeof(int), stream);

    k_hist   <<<(E + 255) / 256, 256, 0, stream>>>(dst, cnt, E);
    k_scan1  <<<NB, 256, 0, stream>>>(cnt, rowptr, blk, N);
    k_scan2  <<<1, 128, 0, stream>>>(blk, NB);
    k_scan3  <<<(N + 255) / 256, 256, 0, stream>>>(rowptr, blk, cursor, cnt, dinv, x, xs, N);
    k_scatter<<<(E + 255) / 256, 256, 0, stream>>>(src, dst, cursor, srclist, E);

    k_l1fused<<<(N * 32 + 255) / 256, 256, 0, stream>>>(rowptr, cnt, srclist, dinv,
                                                        xs, W1, b1, h1, N);
    k_agg2gemm2<<<(N + 7) / 8, 256, 0, stream>>>(rowptr, cnt, srclist, dinv,
                                                 h1, W2, b2, u, N);
    k7_pool_mlp<<<G, HID, 0, stream>>>(u, batch, Wm1, bm1, Wm2, bm2, out, N);
}

// Round 12
// 579.698 us; speedup vs baseline: 6.5801x; 1.0208x over previous
//
#include <hip/hip_runtime.h>
#include <hip/hip_fp16.h>

#define INCH 10
#define HID 128
#define NGRAPH 1000
#define SCAN_BLK 1024   // elements per scan block

// ======================= CSR build =======================

__global__ void k_hist(const int* __restrict__ dst, int* __restrict__ cnt, int e) {
    int i = blockIdx.x * blockDim.x + threadIdx.x;
    if (i < e) atomicAdd(&cnt[dst[i]], 1);
}

__global__ void k_scan1(const int* __restrict__ cnt, int* __restrict__ rowptr,
                        int* __restrict__ blk, int n) {
    __shared__ int sdata[256];
    int b = blockIdx.x, t = threadIdx.x;
    int base = b * SCAN_BLK + t * 4;
    int v0 = 0, v1 = 0, v2 = 0, v3 = 0;
    if (base + 0 < n) v0 = cnt[base + 0];
    if (base + 1 < n) v1 = cnt[base + 1];
    if (base + 2 < n) v2 = cnt[base + 2];
    if (base + 3 < n) v3 = cnt[base + 3];
    int s = v0 + v1 + v2 + v3;
    sdata[t] = s;
    __syncthreads();
    for (int off = 1; off < 256; off <<= 1) {
        int x = (t >= off) ? sdata[t - off] : 0;
        __syncthreads();
        sdata[t] += x;
        __syncthreads();
    }
    int excl = sdata[t] - s;
    if (t == 255) blk[b] = sdata[255];
    int run = excl;
    if (base + 0 < n) { rowptr[base + 0] = run; run += v0; }
    if (base + 1 < n) { rowptr[base + 1] = run; run += v1; }
    if (base + 2 < n) { rowptr[base + 2] = run; run += v2; }
    if (base + 3 < n) { rowptr[base + 3] = run; }
}

__global__ void k_scan2(int* __restrict__ blk, int nb) {
    __shared__ int s[128];
    int t = threadIdx.x;
    int v = (t < nb) ? blk[t] : 0;
    s[t] = v;
    __syncthreads();
    for (int off = 1; off < 128; off <<= 1) {
        int x = (t >= off) ? s[t - off] : 0;
        __syncthreads();
        s[t] += x;
        __syncthreads();
    }
    if (t < nb) blk[t] = s[t] - v;
}

// scan3 + dinv + xs = dinv*x  (fused epilogue of CSR build)
__global__ void k_scan3(int* __restrict__ rowptr, const int* __restrict__ blk,
                        int* __restrict__ cursor, const int* __restrict__ cnt,
                        float* __restrict__ dinv, const float* __restrict__ x,
                        float* __restrict__ xs, int n) {
    int i = blockIdx.x * blockDim.x + threadIdx.x;
    if (i < n) {
        int r = rowptr[i] + blk[i / SCAN_BLK];
        rowptr[i] = r;
        cursor[i] = r;
        float rv = rsqrtf((float)(cnt[i] + 1));
        dinv[i] = rv;
        #pragma unroll
        for (int c = 0; c < INCH; c++)
            xs[i * INCH + c] = rv * x[i * INCH + c];
    }
}

__global__ void k_scatter(const int* __restrict__ src, const int* __restrict__ dst,
                          int* __restrict__ cursor, int* __restrict__ srclist, int e) {
    int i = blockIdx.x * blockDim.x + threadIdx.x;
    if (i < e) {
        int p = atomicAdd(&cursor[dst[i]], 1);
        srclist[p] = src[i];
    }
}

// ======================= layer 1 fused: agg + GEMM1, outputs h1' = fp16(dinv*relu) ===
__global__ __launch_bounds__(256) void k_l1fused(
        const int* __restrict__ rowptr, const int* __restrict__ cnt,
        const int* __restrict__ srclist, const float* __restrict__ dinv,
        const float* __restrict__ xs, const float* __restrict__ W1,
        const float* __restrict__ b1, __half* __restrict__ h1, int n) {
    int t = blockIdx.x * blockDim.x + threadIdx.x;
    int node = t >> 5;              // 32 lanes per node
    int l32 = t & 31;
    if (node >= n) return;

    int lo = rowptr[node], deg = cnt[node];
    float acc[INCH];
    #pragma unroll
    for (int c = 0; c < INCH; c++) acc[c] = 0.0f;

    for (int e = lo + l32; e < lo + deg; e += 32) {
        int s = srclist[e];
        #pragma unroll
        for (int c = 0; c < INCH; c++)
            acc[c] += xs[s * INCH + c];          // xs already dinv-scaled
    }
    #pragma unroll
    for (int m = 16; m; m >>= 1) {
        #pragma unroll
        for (int c = 0; c < INCH; c++)
            acc[c] += __shfl_xor(acc[c], m, 32);
    }
    float r = dinv[node];
    float agg[INCH];
    #pragma unroll
    for (int c = 0; c < INCH; c++)
        agg[c] = r * (acc[c] + xs[node * INCH + c]);

    // GEMM1: each lane computes 4 output channels; store h1' = fp16(r*relu(.))
    int j0 = l32 * 4;
    float4 o = *reinterpret_cast<const float4*>(b1 + j0);
    #pragma unroll
    for (int c = 0; c < INCH; c++) {
        const float4 wv = *reinterpret_cast<const float4*>(W1 + c * HID + j0);
        o.x = fmaf(agg[c], wv.x, o.x);
        o.y = fmaf(agg[c], wv.y, o.y);
        o.z = fmaf(agg[c], wv.z, o.z);
        o.w = fmaf(agg[c], wv.w, o.w);
    }
    __half2 p0 = __floats2half2_rn(r * fmaxf(o.x, 0.f), r * fmaxf(o.y, 0.f));
    __half2 p1 = __floats2half2_rn(r * fmaxf(o.z, 0.f), r * fmaxf(o.w, 0.f));
    uint2 pk;
    pk.x = *reinterpret_cast<unsigned int*>(&p0);
    pk.y = *reinterpret_cast<unsigned int*>(&p1);
    *reinterpret_cast<uint2*>(h1 + (size_t)node * HID + j0) = pk;
}

// ======================= layer 2 fused: agg + GEMM2 =======================
// h1' is fp16, pre-scaled. agg2 = r*(sum h1'[s] + h1'[d]). 8 nodes/block,
// 32 lanes x 4ch (uint2 = 8B/lane). 4-deep unrolled gather.
__device__ __forceinline__ float4 ld_h4(const __half* p) {
    uint2 pk = *reinterpret_cast<const uint2*>(p);
    __half2 p0 = *reinterpret_cast<__half2*>(&pk.x);
    __half2 p1 = *reinterpret_cast<__half2*>(&pk.y);
    float2 f0 = __half22float2(p0);
    float2 f1 = __half22float2(p1);
    return make_float4(f0.x, f0.y, f1.x, f1.y);
}

__global__ __launch_bounds__(256) void k_agg2gemm2(
        const int* __restrict__ rowptr, const int* __restrict__ cnt,
        const int* __restrict__ srclist, const float* __restrict__ dinv,
        const __half* __restrict__ h1, const float* __restrict__ W2,
        const float* __restrict__ b2, float* __restrict__ u, int n) {
    __shared__ float aggs[8 * HID];       // 4 KB
    int t = threadIdx.x;
    int nl = t >> 5, l32 = t & 31;
    int j0 = l32 * 4;
    int node = blockIdx.x * 8 + nl;

    if (node < n) {
        int lo = rowptr[node], hi = lo + cnt[node];
        float4 acc = make_float4(0.f, 0.f, 0.f, 0.f);
        int e = lo;
        for (; e + 4 <= hi; e += 4) {           // four independent gather chains
            int s0 = srclist[e], s1 = srclist[e + 1];
            int s2 = srclist[e + 2], s3 = srclist[e + 3];
            float4 a0 = ld_h4(h1 + (size_t)s0 * HID + j0);
            float4 a1 = ld_h4(h1 + (size_t)s1 * HID + j0);
            float4 a2 = ld_h4(h1 + (size_t)s2 * HID + j0);
            float4 a3 = ld_h4(h1 + (size_t)s3 * HID + j0);
            acc.x += a0.x + a1.x + a2.x + a3.x;
            acc.y += a0.y + a1.y + a2.y + a3.y;
            acc.z += a0.z + a1.z + a2.z + a3.z;
            acc.w += a0.w + a1.w + a2.w + a3.w;
        }
        for (; e < hi; e++) {
            int s0 = srclist[e];
            float4 a0 = ld_h4(h1 + (size_t)s0 * HID + j0);
            acc.x += a0.x; acc.y += a0.y; acc.z += a0.z; acc.w += a0.w;
        }
        float r = dinv[node];
        float4 hs = ld_h4(h1 + (size_t)node * HID + j0);
        aggs[nl * HID + j0 + 0] = r * (acc.x + hs.x);
        aggs[nl * HID + j0 + 1] = r * (acc.y + hs.y);
        aggs[nl * HID + j0 + 2] = r * (acc.z + hs.z);
        aggs[nl * HID + j0 + 3] = r * (acc.w + hs.w);
    }
    __syncthreads();
    if (node < n) {
        float4 o = *reinterpret_cast<const float4*>(b2 + j0);
        const float* ar = &aggs[nl * HID];
        #pragma unroll 8
        for (int k = 0; k < HID; k++) {
            float av = ar[k];                                   // LDS broadcast
            const float4 wv = *reinterpret_cast<const float4*>(W2 + k * HID + j0);  // L1-hit
            o.x = fmaf(av, wv.x, o.x);
            o.y = fmaf(av, wv.y, o.y);
            o.z = fmaf(av, wv.z, o.z);
            o.w = fmaf(av, wv.w, o.w);
        }
        float4 res = make_float4(fmaxf(o.x, 0.f), fmaxf(o.y, 0.f),
                                 fmaxf(o.z, 0.f), fmaxf(o.w, 0.f));
        *reinterpret_cast<float4*>(u + (size_t)node * HID + j0) = res;
    }
}

// ======================= pool + MLP =======================
__global__ void k7_pool_mlp(const float* __restrict__ h2, const int* __restrict__ batch,
                            const float* __restrict__ Wm1, const float* __restrict__ bm1,
                            const float* __restrict__ Wm2, const float* __restrict__ bm2,
                            float* __restrict__ out, int n) {
    int g = blockIdx.x;
    int j = threadIdx.x;   // 128 threads
    int a = 0, b = n;
    while (a < b) { int m = (a + b) >> 1; if (batch[m] < g) a = m + 1; else b = m; }
    int lo = a;
    b = n;
    while (a < b) { int m = (a + b) >> 1; if (batch[m] < g + 1) a = m + 1; else b = m; }
    int hi = a;

    float sum = 0.0f;
    for (int i = lo; i < hi; i++) sum += h2[(size_t)i * HID + j];
    float cnt = (float)(hi - lo);
    float gj = sum / fmaxf(cnt, 1.0f);

    __shared__ float gl[HID];
    gl[j] = gj;
    __syncthreads();

    float acc = bm1[j];
    #pragma unroll 8
    for (int k = 0; k < HID; k++) acc = fmaf(gl[k], Wm1[k * HID + j], acc);
    float y = tanhf(acc) * Wm2[j];

    __shared__ float red[HID];
    red[j] = y;
    __syncthreads();
    if (j < 64) {
        float v = red[j] + red[j + 64];
        for (int off = 32; off; off >>= 1) v += __shfl_down(v, off);
        if (j == 0) out[g] = v + bm2[0];
    }
}

extern "C" void kernel_launch(void* const* d_in, const int* in_sizes, int n_in,
                              void* d_out, int out_size, void* d_ws, size_t ws_size,
                              hipStream_t stream) {
    const float* x    = (const float*)d_in[0];
    const int*   ei   = (const int*)d_in[1];
    const int*   batch= (const int*)d_in[2];
    const float* W1   = (const float*)d_in[4];
    const float* b1   = (const float*)d_in[5];
    const float* W2   = (const float*)d_in[6];
    const float* b2   = (const float*)d_in[7];
    const float* Wm1  = (const float*)d_in[8];
    const float* bm1  = (const float*)d_in[9];
    const float* Wm2  = (const float*)d_in[10];
    const float* bm2  = (const float*)d_in[11];
    float* out = (float*)d_out;

    const int N = in_sizes[0] / INCH;       // 100000
    const int E = in_sizes[1] / 2;          // 1600000
    const int G = NGRAPH;                   // 1000
    const int NB = (N + SCAN_BLK - 1) / SCAN_BLK;   // 98 (<=128 required by k_scan2)

    char* w = (char*)d_ws;
    int*    cnt     = (int*)w;     w += (size_t)N * 4;
    int*    rowptr  = (int*)w;     w += (size_t)N * 4;
    int*    cursor  = (int*)w;     w += (size_t)N * 4;
    int*    blk     = (int*)w;     w += 256 * 4;
    float*  dinv    = (float*)w;   w += (size_t)N * 4;
    float*  xs      = (float*)w;   w += (size_t)N * INCH * 4;
    int*    srclist = (int*)w;     w += (size_t)E * 4;
    __half* h1      = (__half*)w;  w += (size_t)N * HID * 2;  // h1' fp16 (25.6 MB)
    float*  u       = (float*)w;   w += (size_t)N * HID * 4;  // h2 output

    const int* src = ei;
    const int* dst = ei + E;

    hipMemsetAsync(cnt, 0, (size_t)N * sizeof(int), stream);

    k_hist   <<<(E + 255) / 256, 256, 0, stream>>>(dst, cnt, E);
    k_scan1  <<<NB, 256, 0, stream>>>(cnt, rowptr, blk, N);
    k_scan2  <<<1, 128, 0, stream>>>(blk, NB);
    k_scan3  <<<(N + 255) / 256, 256, 0, stream>>>(rowptr, blk, cursor, cnt, dinv, x, xs, N);
    k_scatter<<<(E + 255) / 256, 256, 0, stream>>>(src, dst, cursor, srclist, E);

    k_l1fused<<<(N * 32 + 255) / 256, 256, 0, stream>>>(rowptr, cnt, srclist, dinv,
                                                        xs, W1, b1, h1, N);
    k_agg2gemm2<<<(N + 7) / 8, 256, 0, stream>>>(rowptr, cnt, srclist, dinv,
                                                 h1, W2, b2, u, N);
    k7_pool_mlp<<<G, HID, 0, stream>>>(u, batch, Wm1, bm1, Wm2, bm2, out, N);
}

// Round 13
// 567.488 us; speedup vs baseline: 6.7217x; 1.0215x over previous
//
#include <hip/hip_runtime.h>
#include <hip/hip_fp16.h>

#define INCH 10
#define XSP 12          // padded xs stride (12 floats = 48 B, 16B-aligned rows)
#define HID 128
#define NGRAPH 1000
#define SCAN_BLK 1024   // elements per scan block

// ======================= CSR build =======================

__global__ void k_hist(const int* __restrict__ dst, int* __restrict__ cnt, int e) {
    int i = blockIdx.x * blockDim.x + threadIdx.x;
    if (i < e) atomicAdd(&cnt[dst[i]], 1);
}

__global__ void k_scan1(const int* __restrict__ cnt, int* __restrict__ rowptr,
                        int* __restrict__ blk, int n) {
    __shared__ int sdata[256];
    int b = blockIdx.x, t = threadIdx.x;
    int base = b * SCAN_BLK + t * 4;
    int v0 = 0, v1 = 0, v2 = 0, v3 = 0;
    if (base + 0 < n) v0 = cnt[base + 0];
    if (base + 1 < n) v1 = cnt[base + 1];
    if (base + 2 < n) v2 = cnt[base + 2];
    if (base + 3 < n) v3 = cnt[base + 3];
    int s = v0 + v1 + v2 + v3;
    sdata[t] = s;
    __syncthreads();
    for (int off = 1; off < 256; off <<= 1) {
        int x = (t >= off) ? sdata[t - off] : 0;
        __syncthreads();
        sdata[t] += x;
        __syncthreads();
    }
    int excl = sdata[t] - s;
    if (t == 255) blk[b] = sdata[255];
    int run = excl;
    if (base + 0 < n) { rowptr[base + 0] = run; run += v0; }
    if (base + 1 < n) { rowptr[base + 1] = run; run += v1; }
    if (base + 2 < n) { rowptr[base + 2] = run; run += v2; }
    if (base + 3 < n) { rowptr[base + 3] = run; }
}

__global__ void k_scan2(int* __restrict__ blk, int nb) {
    __shared__ int s[128];
    int t = threadIdx.x;
    int v = (t < nb) ? blk[t] : 0;
    s[t] = v;
    __syncthreads();
    for (int off = 1; off < 128; off <<= 1) {
        int x = (t >= off) ? s[t - off] : 0;
        __syncthreads();
        s[t] += x;
        __syncthreads();
    }
    if (t < nb) blk[t] = s[t] - v;
}

// scan3 + dinv + xs = dinv*x (padded stride 12)  (fused epilogue of CSR build)
__global__ void k_scan3(int* __restrict__ rowptr, const int* __restrict__ blk,
                        int* __restrict__ cursor, const int* __restrict__ cnt,
                        float* __restrict__ dinv, const float* __restrict__ x,
                        float* __restrict__ xs, int n) {
    int i = blockIdx.x * blockDim.x + threadIdx.x;
    if (i < n) {
        int r = rowptr[i] + blk[i / SCAN_BLK];
        rowptr[i] = r;
        cursor[i] = r;
        float rv = rsqrtf((float)(cnt[i] + 1));
        dinv[i] = rv;
        #pragma unroll
        for (int c = 0; c < INCH; c++)
            xs[i * XSP + c] = rv * x[i * INCH + c];
        xs[i * XSP + 10] = 0.0f;
        xs[i * XSP + 11] = 0.0f;
    }
}

__global__ void k_scatter(const int* __restrict__ src, const int* __restrict__ dst,
                          int* __restrict__ cursor, int* __restrict__ srclist, int e) {
    int i = blockIdx.x * blockDim.x + threadIdx.x;
    if (i < e) {
        int p = atomicAdd(&cursor[dst[i]], 1);
        srclist[p] = src[i];
    }
}

// W2 -> fp16 (32 KB, fits L1)
__global__ void k_w2h(const float* __restrict__ W2, __half* __restrict__ W2h, int sz) {
    int i = blockIdx.x * blockDim.x + threadIdx.x;
    if (i < sz) W2h[i] = __float2half(W2[i]);
}

// ======================= layer 1 fused: agg + GEMM1, outputs h1' = fp16(dinv*relu) ===
__global__ __launch_bounds__(256) void k_l1fused(
        const int* __restrict__ rowptr, const int* __restrict__ cnt,
        const int* __restrict__ srclist, const float* __restrict__ dinv,
        const float* __restrict__ xs, const float* __restrict__ W1,
        const float* __restrict__ b1, __half* __restrict__ h1, int n) {
    int t = blockIdx.x * blockDim.x + threadIdx.x;
    int node = t >> 5;              // 32 lanes per node
    int l32 = t & 31;
    if (node >= n) return;

    int lo = rowptr[node], deg = cnt[node];
    float acc[INCH];
    #pragma unroll
    for (int c = 0; c < INCH; c++) acc[c] = 0.0f;

    for (int e = lo + l32; e < lo + deg; e += 32) {
        int s = srclist[e];
        const float4* xr = reinterpret_cast<const float4*>(xs + (size_t)s * XSP);
        float4 v0 = xr[0];
        float4 v1 = xr[1];
        float2 v2 = *reinterpret_cast<const float2*>(xs + (size_t)s * XSP + 8);
        acc[0] += v0.x; acc[1] += v0.y; acc[2] += v0.z; acc[3] += v0.w;
        acc[4] += v1.x; acc[5] += v1.y; acc[6] += v1.z; acc[7] += v1.w;
        acc[8] += v2.x; acc[9] += v2.y;
    }
    #pragma unroll
    for (int m = 16; m; m >>= 1) {
        #pragma unroll
        for (int c = 0; c < INCH; c++)
            acc[c] += __shfl_xor(acc[c], m, 32);
    }
    float r = dinv[node];
    float agg[INCH];
    #pragma unroll
    for (int c = 0; c < INCH; c++)
        agg[c] = r * (acc[c] + xs[node * XSP + c]);

    // GEMM1: each lane computes 4 output channels; store h1' = fp16(r*relu(.))
    int j0 = l32 * 4;
    float4 o = *reinterpret_cast<const float4*>(b1 + j0);
    #pragma unroll
    for (int c = 0; c < INCH; c++) {
        const float4 wv = *reinterpret_cast<const float4*>(W1 + c * HID + j0);
        o.x = fmaf(agg[c], wv.x, o.x);
        o.y = fmaf(agg[c], wv.y, o.y);
        o.z = fmaf(agg[c], wv.z, o.z);
        o.w = fmaf(agg[c], wv.w, o.w);
    }
    __half2 p0 = __floats2half2_rn(r * fmaxf(o.x, 0.f), r * fmaxf(o.y, 0.f));
    __half2 p1 = __floats2half2_rn(r * fmaxf(o.z, 0.f), r * fmaxf(o.w, 0.f));
    uint2 pk;
    pk.x = *reinterpret_cast<unsigned int*>(&p0);
    pk.y = *reinterpret_cast<unsigned int*>(&p1);
    *reinterpret_cast<uint2*>(h1 + (size_t)node * HID + j0) = pk;
}

// ======================= layer 2 fused: agg + GEMM2 =======================
__device__ __forceinline__ float4 ld_h4(const __half* p) {
    uint2 pk = *reinterpret_cast<const uint2*>(p);
    __half2 p0 = *reinterpret_cast<__half2*>(&pk.x);
    __half2 p1 = *reinterpret_cast<__half2*>(&pk.y);
    float2 f0 = __half22float2(p0);
    float2 f1 = __half22float2(p1);
    return make_float4(f0.x, f0.y, f1.x, f1.y);
}

__global__ __launch_bounds__(256) void k_agg2gemm2(
        const int* __restrict__ rowptr, const int* __restrict__ cnt,
        const int* __restrict__ srclist, const float* __restrict__ dinv,
        const __half* __restrict__ h1, const __half* __restrict__ W2h,
        const float* __restrict__ b2, float* __restrict__ u, int n) {
    __shared__ float aggs[8 * HID];       // 4 KB
    int t = threadIdx.x;
    int nl = t >> 5, l32 = t & 31;
    int j0 = l32 * 4;
    int node = blockIdx.x * 8 + nl;

    if (node < n) {
        int lo = rowptr[node], hi = lo + cnt[node];
        float4 acc = make_float4(0.f, 0.f, 0.f, 0.f);
        int e = lo;
        for (; e + 4 <= hi; e += 4) {           // four independent gather chains
            int s0 = srclist[e], s1 = srclist[e + 1];
            int s2 = srclist[e + 2], s3 = srclist[e + 3];
            float4 a0 = ld_h4(h1 + (size_t)s0 * HID + j0);
            float4 a1 = ld_h4(h1 + (size_t)s1 * HID + j0);
            float4 a2 = ld_h4(h1 + (size_t)s2 * HID + j0);
            float4 a3 = ld_h4(h1 + (size_t)s3 * HID + j0);
            acc.x += a0.x + a1.x + a2.x + a3.x;
            acc.y += a0.y + a1.y + a2.y + a3.y;
            acc.z += a0.z + a1.z + a2.z + a3.z;
            acc.w += a0.w + a1.w + a2.w + a3.w;
        }
        for (; e < hi; e++) {
            int s0 = srclist[e];
            float4 a0 = ld_h4(h1 + (size_t)s0 * HID + j0);
            acc.x += a0.x; acc.y += a0.y; acc.z += a0.z; acc.w += a0.w;
        }
        float r = dinv[node];
        float4 hs = ld_h4(h1 + (size_t)node * HID + j0);
        aggs[nl * HID + j0 + 0] = r * (acc.x + hs.x);
        aggs[nl * HID + j0 + 1] = r * (acc.y + hs.y);
        aggs[nl * HID + j0 + 2] = r * (acc.z + hs.z);
        aggs[nl * HID + j0 + 3] = r * (acc.w + hs.w);
    }
    __syncthreads();
    if (node < n) {
        float4 o = *reinterpret_cast<const float4*>(b2 + j0);
        const float4* ar4 = reinterpret_cast<const float4*>(&aggs[nl * HID]);
        #pragma unroll 8
        for (int k4 = 0; k4 < HID / 4; k4++) {
            float4 av = ar4[k4];                 // one ds_read_b128, broadcast
            float4 w0 = ld_h4(W2h + (4 * k4 + 0) * HID + j0);   // L1-resident fp16
            float4 w1 = ld_h4(W2h + (4 * k4 + 1) * HID + j0);
            float4 w2 = ld_h4(W2h + (4 * k4 + 2) * HID + j0);
            float4 w3 = ld_h4(W2h + (4 * k4 + 3) * HID + j0);
            o.x = fmaf(av.x, w0.x, o.x); o.y = fmaf(av.x, w0.y, o.y);
            o.z = fmaf(av.x, w0.z, o.z); o.w = fmaf(av.x, w0.w, o.w);
            o.x = fmaf(av.y, w1.x, o.x); o.y = fmaf(av.y, w1.y, o.y);
            o.z = fmaf(av.y, w1.z, o.z); o.w = fmaf(av.y, w1.w, o.w);
            o.x = fmaf(av.z, w2.x, o.x); o.y = fmaf(av.z, w2.y, o.y);
            o.z = fmaf(av.z, w2.z, o.z); o.w = fmaf(av.z, w2.w, o.w);
            o.x = fmaf(av.w, w3.x, o.x); o.y = fmaf(av.w, w3.y, o.y);
            o.z = fmaf(av.w, w3.z, o.z); o.w = fmaf(av.w, w3.w, o.w);
        }
        float4 res = make_float4(fmaxf(o.x, 0.f), fmaxf(o.y, 0.f),
                                 fmaxf(o.z, 0.f), fmaxf(o.w, 0.f));
        *reinterpret_cast<float4*>(u + (size_t)node * HID + j0) = res;
    }
}

// ======================= pool + MLP =======================
__global__ void k7_pool_mlp(const float* __restrict__ h2, const int* __restrict__ batch,
                            const float* __restrict__ Wm1, const float* __restrict__ bm1,
                            const float* __restrict__ Wm2, const float* __restrict__ bm2,
                            float* __restrict__ out, int n) {
    int g = blockIdx.x;
    int j = threadIdx.x;   // 128 threads
    int a = 0, b = n;
    while (a < b) { int m = (a + b) >> 1; if (batch[m] < g) a = m + 1; else b = m; }
    int lo = a;
    b = n;
    while (a < b) { int m = (a + b) >> 1; if (batch[m] < g + 1) a = m + 1; else b = m; }
    int hi = a;

    float sum = 0.0f;
    for (int i = lo; i < hi; i++) sum += h2[(size_t)i * HID + j];
    float cnt = (float)(hi - lo);
    float gj = sum / fmaxf(cnt, 1.0f);

    __shared__ float gl[HID];
    gl[j] = gj;
    __syncthreads();

    float acc = bm1[j];
    #pragma unroll 8
    for (int k = 0; k < HID; k++) acc = fmaf(gl[k], Wm1[k * HID + j], acc);
    float y = tanhf(acc) * Wm2[j];

    __shared__ float red[HID];
    red[j] = y;
    __syncthreads();
    if (j < 64) {
        float v = red[j] + red[j + 64];
        for (int off = 32; off; off >>= 1) v += __shfl_down(v, off);
        if (j == 0) out[g] = v + bm2[0];
    }
}

extern "C" void kernel_launch(void* const* d_in, const int* in_sizes, int n_in,
                              void* d_out, int out_size, void* d_ws, size_t ws_size,
                              hipStream_t stream) {
    const float* x    = (const float*)d_in[0];
    const int*   ei   = (const int*)d_in[1];
    const int*   batch= (const int*)d_in[2];
    const float* W1   = (const float*)d_in[4];
    const float* b1   = (const float*)d_in[5];
    const float* W2   = (const float*)d_in[6];
    const float* b2   = (const float*)d_in[7];
    const float* Wm1  = (const float*)d_in[8];
    const float* bm1  = (const float*)d_in[9];
    const float* Wm2  = (const float*)d_in[10];
    const float* bm2  = (const float*)d_in[11];
    float* out = (float*)d_out;

    const int N = in_sizes[0] / INCH;       // 100000
    const int E = in_sizes[1] / 2;          // 1600000
    const int G = NGRAPH;                   // 1000
    const int NB = (N + SCAN_BLK - 1) / SCAN_BLK;   // 98 (<=128 required by k_scan2)

    char* w = (char*)d_ws;
    int*    cnt     = (int*)w;     w += (size_t)N * 4;
    int*    rowptr  = (int*)w;     w += (size_t)N * 4;
    int*    cursor  = (int*)w;     w += (size_t)N * 4;
    int*    blk     = (int*)w;     w += 256 * 4;
    float*  dinv    = (float*)w;   w += (size_t)N * 4;
    float*  xs      = (float*)w;   w += (size_t)N * XSP * 4;   // padded stride 12
    int*    srclist = (int*)w;     w += (size_t)E * 4;
    __half* h1      = (__half*)w;  w += (size_t)N * HID * 2;   // h1' fp16 (25.6 MB)
    __half* W2h     = (__half*)w;  w += (size_t)HID * HID * 2; // 32 KB fp16 W2
    float*  u       = (float*)w;   w += (size_t)N * HID * 4;   // h2 output

    const int* src = ei;
    const int* dst = ei + E;

    hipMemsetAsync(cnt, 0, (size_t)N * sizeof(int), stream);

    k_hist   <<<(E + 255) / 256, 256, 0, stream>>>(dst, cnt, E);
    k_w2h    <<<(HID * HID + 255) / 256, 256, 0, stream>>>(W2, W2h, HID * HID);
    k_scan1  <<<NB, 256, 0, stream>>>(cnt, rowptr, blk, N);
    k_scan2  <<<1, 128, 0, stream>>>(blk, NB);
    k_scan3  <<<(N + 255) / 256, 256, 0, stream>>>(rowptr, blk, cursor, cnt, dinv, x, xs, N);
    k_scatter<<<(E + 255) / 256, 256, 0, stream>>>(src, dst, cursor, srclist, E);

    k_l1fused<<<(N * 32 + 255) / 256, 256, 0, stream>>>(rowptr, cnt, srclist, dinv,
                                                        xs, W1, b1, h1, N);
    k_agg2gemm2<<<(N + 7) / 8, 256, 0, stream>>>(rowptr, cnt, srclist, dinv,
                                                 h1, W2h, b2, u, N);
    k7_pool_mlp<<<G, HID, 0, stream>>>(u, batch, Wm1, bm1, Wm2, bm2, out, N);
}

// Round 14
// 504.548 us; speedup vs baseline: 7.5602x; 1.1247x over previous
//
#include <hip/hip_runtime.h>
#include <hip/hip_fp16.h>

#define INCH 10
#define XSP 12          // padded xs stride (12 floats = 48 B, 16B-aligned rows)
#define HID 128
#define NGRAPH 1000
#define SCAN_BLK 1024   // elements per scan block

// ======================= CSR build =======================

__global__ void k_hist(const int* __restrict__ dst, int* __restrict__ cnt, int e) {
    int i = blockIdx.x * blockDim.x + threadIdx.x;
    if (i < e) atomicAdd(&cnt[dst[i]], 1);
}

__global__ void k_scan1(const int* __restrict__ cnt, int* __restrict__ rowptr,
                        int* __restrict__ blk, int n) {
    __shared__ int sdata[256];
    int b = blockIdx.x, t = threadIdx.x;
    int base = b * SCAN_BLK + t * 4;
    int v0 = 0, v1 = 0, v2 = 0, v3 = 0;
    if (base + 0 < n) v0 = cnt[base + 0];
    if (base + 1 < n) v1 = cnt[base + 1];
    if (base + 2 < n) v2 = cnt[base + 2];
    if (base + 3 < n) v3 = cnt[base + 3];
    int s = v0 + v1 + v2 + v3;
    sdata[t] = s;
    __syncthreads();
    for (int off = 1; off < 256; off <<= 1) {
        int x = (t >= off) ? sdata[t - off] : 0;
        __syncthreads();
        sdata[t] += x;
        __syncthreads();
    }
    int excl = sdata[t] - s;
    if (t == 255) blk[b] = sdata[255];
    int run = excl;
    if (base + 0 < n) { rowptr[base + 0] = run; run += v0; }
    if (base + 1 < n) { rowptr[base + 1] = run; run += v1; }
    if (base + 2 < n) { rowptr[base + 2] = run; run += v2; }
    if (base + 3 < n) { rowptr[base + 3] = run; }
}

__global__ void k_scan2(int* __restrict__ blk, int nb) {
    __shared__ int s[128];
    int t = threadIdx.x;
    int v = (t < nb) ? blk[t] : 0;
    s[t] = v;
    __syncthreads();
    for (int off = 1; off < 128; off <<= 1) {
        int x = (t >= off) ? s[t - off] : 0;
        __syncthreads();
        s[t] += x;
        __syncthreads();
    }
    if (t < nb) blk[t] = s[t] - v;
}

// scan3 + dinv + xs = dinv*x (padded stride 12)  (fused epilogue of CSR build)
__global__ void k_scan3(int* __restrict__ rowptr, const int* __restrict__ blk,
                        int* __restrict__ cursor, const int* __restrict__ cnt,
                        float* __restrict__ dinv, const float* __restrict__ x,
                        float* __restrict__ xs, int n) {
    int i = blockIdx.x * blockDim.x + threadIdx.x;
    if (i < n) {
        int r = rowptr[i] + blk[i / SCAN_BLK];
        rowptr[i] = r;
        cursor[i] = r;
        float rv = rsqrtf((float)(cnt[i] + 1));
        dinv[i] = rv;
        #pragma unroll
        for (int c = 0; c < INCH; c++)
            xs[i * XSP + c] = rv * x[i * INCH + c];
        xs[i * XSP + 10] = 0.0f;
        xs[i * XSP + 11] = 0.0f;
    }
}

__global__ void k_scatter(const int* __restrict__ src, const int* __restrict__ dst,
                          int* __restrict__ cursor, int* __restrict__ srclist, int e) {
    int i = blockIdx.x * blockDim.x + threadIdx.x;
    if (i < e) {
        int p = atomicAdd(&cursor[dst[i]], 1);
        srclist[p] = src[i];
    }
}

// W2 -> fp16
__global__ void k_w2h(const float* __restrict__ W2, __half* __restrict__ W2h, int sz) {
    int i = blockIdx.x * blockDim.x + threadIdx.x;
    if (i < sz) W2h[i] = __float2half(W2[i]);
}

// ======================= layer 1 fused: agg + GEMM1, outputs h1' = fp16(dinv*relu) ===
__global__ __launch_bounds__(256) void k_l1fused(
        const int* __restrict__ rowptr, const int* __restrict__ cnt,
        const int* __restrict__ srclist, const float* __restrict__ dinv,
        const float* __restrict__ xs, const float* __restrict__ W1,
        const float* __restrict__ b1, __half* __restrict__ h1, int n) {
    int t = blockIdx.x * blockDim.x + threadIdx.x;
    int node = t >> 5;              // 32 lanes per node
    int l32 = t & 31;
    if (node >= n) return;

    int lo = rowptr[node], deg = cnt[node];
    float acc[INCH];
    #pragma unroll
    for (int c = 0; c < INCH; c++) acc[c] = 0.0f;

    for (int e = lo + l32; e < lo + deg; e += 32) {
        int s = srclist[e];
        const float4* xr = reinterpret_cast<const float4*>(xs + (size_t)s * XSP);
        float4 v0 = xr[0];
        float4 v1 = xr[1];
        float2 v2 = *reinterpret_cast<const float2*>(xs + (size_t)s * XSP + 8);
        acc[0] += v0.x; acc[1] += v0.y; acc[2] += v0.z; acc[3] += v0.w;
        acc[4] += v1.x; acc[5] += v1.y; acc[6] += v1.z; acc[7] += v1.w;
        acc[8] += v2.x; acc[9] += v2.y;
    }
    #pragma unroll
    for (int m = 16; m; m >>= 1) {
        #pragma unroll
        for (int c = 0; c < INCH; c++)
            acc[c] += __shfl_xor(acc[c], m, 32);
    }
    float r = dinv[node];
    float agg[INCH];
    #pragma unroll
    for (int c = 0; c < INCH; c++)
        agg[c] = r * (acc[c] + xs[node * XSP + c]);

    // GEMM1: each lane computes 4 output channels; store h1' = fp16(r*relu(.))
    int j0 = l32 * 4;
    float4 o = *reinterpret_cast<const float4*>(b1 + j0);
    #pragma unroll
    for (int c = 0; c < INCH; c++) {
        const float4 wv = *reinterpret_cast<const float4*>(W1 + c * HID + j0);
        o.x = fmaf(agg[c], wv.x, o.x);
        o.y = fmaf(agg[c], wv.y, o.y);
        o.z = fmaf(agg[c], wv.z, o.z);
        o.w = fmaf(agg[c], wv.w, o.w);
    }
    __half2 p0 = __floats2half2_rn(r * fmaxf(o.x, 0.f), r * fmaxf(o.y, 0.f));
    __half2 p1 = __floats2half2_rn(r * fmaxf(o.z, 0.f), r * fmaxf(o.w, 0.f));
    uint2 pk;
    pk.x = *reinterpret_cast<unsigned int*>(&p0);
    pk.y = *reinterpret_cast<unsigned int*>(&p1);
    *reinterpret_cast<uint2*>(h1 + (size_t)node * HID + j0) = pk;
}

// ======================= layer 2 fused: agg + GEMM2 =======================
__device__ __forceinline__ float4 ld_h4(const __half* p) {
    uint2 pk = *reinterpret_cast<const uint2*>(p);
    __half2 p0 = *reinterpret_cast<__half2*>(&pk.x);
    __half2 p1 = *reinterpret_cast<__half2*>(&pk.y);
    float2 f0 = __half22float2(p0);
    float2 f1 = __half22float2(p1);
    return make_float4(f0.x, f0.y, f1.x, f1.y);
}

__device__ __forceinline__ float4 ld_h4s(const __half* p) {   // LDS variant
    uint2 pk = *reinterpret_cast<const uint2*>(p);
    __half2 p0 = *reinterpret_cast<__half2*>(&pk.x);
    __half2 p1 = *reinterpret_cast<__half2*>(&pk.y);
    float2 f0 = __half22float2(p0);
    float2 f1 = __half22float2(p1);
    return make_float4(f0.x, f0.y, f1.x, f1.y);
}

__global__ __launch_bounds__(256) void k_agg2gemm2(
        const int* __restrict__ rowptr, const int* __restrict__ cnt,
        const int* __restrict__ srclist, const float* __restrict__ dinv,
        const __half* __restrict__ h1, const __half* __restrict__ W2h,
        const float* __restrict__ b2, float* __restrict__ u, int n) {
    __shared__ __half W2s[HID * HID];     // 32 KB fp16 — eviction-immune W2
    __shared__ float aggs[8 * HID];       // 4 KB
    int t = threadIdx.x;
    // stage W2h -> LDS: 16384 halves, 256 thr x 8 halves (16B) x 8 iters
    for (int i = t * 8; i < HID * HID; i += 256 * 8)
        *reinterpret_cast<uint4*>(&W2s[i]) = *reinterpret_cast<const uint4*>(&W2h[i]);
    __syncthreads();

    int nl = t >> 5, l32 = t & 31;
    int j0 = l32 * 4;
    int node = blockIdx.x * 8 + nl;

    if (node < n) {
        int lo = rowptr[node], hi = lo + cnt[node];
        float4 acc = make_float4(0.f, 0.f, 0.f, 0.f);
        int e = lo;
        for (; e + 8 <= hi; e += 8) {           // eight independent gather chains
            int s0 = srclist[e],     s1 = srclist[e + 1];
            int s2 = srclist[e + 2], s3 = srclist[e + 3];
            int s4 = srclist[e + 4], s5 = srclist[e + 5];
            int s6 = srclist[e + 6], s7 = srclist[e + 7];
            float4 a0 = ld_h4(h1 + (size_t)s0 * HID + j0);
            float4 a1 = ld_h4(h1 + (size_t)s1 * HID + j0);
            float4 a2 = ld_h4(h1 + (size_t)s2 * HID + j0);
            float4 a3 = ld_h4(h1 + (size_t)s3 * HID + j0);
            float4 a4 = ld_h4(h1 + (size_t)s4 * HID + j0);
            float4 a5 = ld_h4(h1 + (size_t)s5 * HID + j0);
            float4 a6 = ld_h4(h1 + (size_t)s6 * HID + j0);
            float4 a7 = ld_h4(h1 + (size_t)s7 * HID + j0);
            acc.x += (a0.x + a1.x) + (a2.x + a3.x) + ((a4.x + a5.x) + (a6.x + a7.x));
            acc.y += (a0.y + a1.y) + (a2.y + a3.y) + ((a4.y + a5.y) + (a6.y + a7.y));
            acc.z += (a0.z + a1.z) + (a2.z + a3.z) + ((a4.z + a5.z) + (a6.z + a7.z));
            acc.w += (a0.w + a1.w) + (a2.w + a3.w) + ((a4.w + a5.w) + (a6.w + a7.w));
        }
        for (; e < hi; e++) {
            int s0 = srclist[e];
            float4 a0 = ld_h4(h1 + (size_t)s0 * HID + j0);
            acc.x += a0.x; acc.y += a0.y; acc.z += a0.z; acc.w += a0.w;
        }
        float r = dinv[node];
        float4 hs = ld_h4(h1 + (size_t)node * HID + j0);
        aggs[nl * HID + j0 + 0] = r * (acc.x + hs.x);
        aggs[nl * HID + j0 + 1] = r * (acc.y + hs.y);
        aggs[nl * HID + j0 + 2] = r * (acc.z + hs.z);
        aggs[nl * HID + j0 + 3] = r * (acc.w + hs.w);
    }
    __syncthreads();
    if (node < n) {
        float4 o = *reinterpret_cast<const float4*>(b2 + j0);
        const float4* ar4 = reinterpret_cast<const float4*>(&aggs[nl * HID]);
        #pragma unroll 8
        for (int k4 = 0; k4 < HID / 4; k4++) {
            float4 av = ar4[k4];                 // ds_read_b128 broadcast
            float4 w0 = ld_h4s(W2s + (4 * k4 + 0) * HID + j0);   // ds_read_b64
            float4 w1 = ld_h4s(W2s + (4 * k4 + 1) * HID + j0);
            float4 w2 = ld_h4s(W2s + (4 * k4 + 2) * HID + j0);
            float4 w3 = ld_h4s(W2s + (4 * k4 + 3) * HID + j0);
            o.x = fmaf(av.x, w0.x, o.x); o.y = fmaf(av.x, w0.y, o.y);
            o.z = fmaf(av.x, w0.z, o.z); o.w = fmaf(av.x, w0.w, o.w);
            o.x = fmaf(av.y, w1.x, o.x); o.y = fmaf(av.y, w1.y, o.y);
            o.z = fmaf(av.y, w1.z, o.z); o.w = fmaf(av.y, w1.w, o.w);
            o.x = fmaf(av.z, w2.x, o.x); o.y = fmaf(av.z, w2.y, o.y);
            o.z = fmaf(av.z, w2.z, o.z); o.w = fmaf(av.z, w2.w, o.w);
            o.x = fmaf(av.w, w3.x, o.x); o.y = fmaf(av.w, w3.y, o.y);
            o.z = fmaf(av.w, w3.z, o.z); o.w = fmaf(av.w, w3.w, o.w);
        }
        float4 res = make_float4(fmaxf(o.x, 0.f), fmaxf(o.y, 0.f),
                                 fmaxf(o.z, 0.f), fmaxf(o.w, 0.f));
        *reinterpret_cast<float4*>(u + (size_t)node * HID + j0) = res;
    }
}

// ======================= pool + MLP =======================
__global__ void k7_pool_mlp(const float* __restrict__ h2, const int* __restrict__ batch,
                            const float* __restrict__ Wm1, const float* __restrict__ bm1,
                            const float* __restrict__ Wm2, const float* __restrict__ bm2,
                            float* __restrict__ out, int n) {
    int g = blockIdx.x;
    int j = threadIdx.x;   // 128 threads
    int a = 0, b = n;
    while (a < b) { int m = (a + b) >> 1; if (batch[m] < g) a = m + 1; else b = m; }
    int lo = a;
    b = n;
    while (a < b) { int m = (a + b) >> 1; if (batch[m] < g + 1) a = m + 1; else b = m; }
    int hi = a;

    float sum = 0.0f;
    for (int i = lo; i < hi; i++) sum += h2[(size_t)i * HID + j];
    float cnt = (float)(hi - lo);
    float gj = sum / fmaxf(cnt, 1.0f);

    __shared__ float gl[HID];
    gl[j] = gj;
    __syncthreads();

    float acc = bm1[j];
    #pragma unroll 8
    for (int k = 0; k < HID; k++) acc = fmaf(gl[k], Wm1[k * HID + j], acc);
    float y = tanhf(acc) * Wm2[j];

    __shared__ float red[HID];
    red[j] = y;
    __syncthreads();
    if (j < 64) {
        float v = red[j] + red[j + 64];
        for (int off = 32; off; off >>= 1) v += __shfl_down(v, off);
        if (j == 0) out[g] = v + bm2[0];
    }
}

extern "C" void kernel_launch(void* const* d_in, const int* in_sizes, int n_in,
                              void* d_out, int out_size, void* d_ws, size_t ws_size,
                              hipStream_t stream) {
    const float* x    = (const float*)d_in[0];
    const int*   ei   = (const int*)d_in[1];
    const int*   batch= (const int*)d_in[2];
    const float* W1   = (const float*)d_in[4];
    const float* b1   = (const float*)d_in[5];
    const float* W2   = (const float*)d_in[6];
    const float* b2   = (const float*)d_in[7];
    const float* Wm1  = (const float*)d_in[8];
    const float* bm1  = (const float*)d_in[9];
    const float* Wm2  = (const float*)d_in[10];
    const float* bm2  = (const float*)d_in[11];
    float* out = (float*)d_out;

    const int N = in_sizes[0] / INCH;       // 100000
    const int E = in_sizes[1] / 2;          // 1600000
    const int G = NGRAPH;                   // 1000
    const int NB = (N + SCAN_BLK - 1) / SCAN_BLK;   // 98 (<=128 required by k_scan2)

    char* w = (char*)d_ws;
    int*    cnt     = (int*)w;     w += (size_t)N * 4;
    int*    rowptr  = (int*)w;     w += (size_t)N * 4;
    int*    cursor  = (int*)w;     w += (size_t)N * 4;
    int*    blk     = (int*)w;     w += 256 * 4;
    float*  dinv    = (float*)w;   w += (size_t)N * 4;
    float*  xs      = (float*)w;   w += (size_t)N * XSP * 4;   // padded stride 12
    int*    srclist = (int*)w;     w += (size_t)E * 4;
    __half* h1      = (__half*)w;  w += (size_t)N * HID * 2;   // h1' fp16 (25.6 MB)
    __half* W2h     = (__half*)w;  w += (size_t)HID * HID * 2; // 32 KB fp16 W2
    float*  u       = (float*)w;   w += (size_t)N * HID * 4;   // h2 output

    const int* src = ei;
    const int* dst = ei + E;

    hipMemsetAsync(cnt, 0, (size_t)N * sizeof(int), stream);

    k_hist   <<<(E + 255) / 256, 256, 0, stream>>>(dst, cnt, E);
    k_w2h    <<<(HID * HID + 255) / 256, 256, 0, stream>>>(W2, W2h, HID * HID);
    k_scan1  <<<NB, 256, 0, stream>>>(cnt, rowptr, blk, N);
    k_scan2  <<<1, 128, 0, stream>>>(blk, NB);
    k_scan3  <<<(N + 255) / 256, 256, 0, stream>>>(rowptr, blk, cursor, cnt, dinv, x, xs, N);
    k_scatter<<<(E + 255) / 256, 256, 0, stream>>>(src, dst, cursor, srclist, E);

    k_l1fused<<<(N * 32 + 255) / 256, 256, 0, stream>>>(rowptr, cnt, srclist, dinv,
                                                        xs, W1, b1, h1, N);
    k_agg2gemm2<<<(N + 7) / 8, 256, 0, stream>>>(rowptr, cnt, srclist, dinv,
                                                 h1, W2h, b2, u, N);
    k7_pool_mlp<<<G, HID, 0, stream>>>(u, batch, Wm1, bm1, Wm2, bm2, out, N);
}

// Round 15
// 455.164 us; speedup vs baseline: 8.3805x; 1.1085x over previous
//
#include <hip/hip_runtime.h>
#include <hip/hip_fp16.h>

#define INCH 10
#define XSP 12          // padded xs stride (12 floats = 48 B, 16B-aligned rows)
#define HID 128
#define NGRAPH 1000
#define SCAN_BLK 1024   // elements per scan block

// ======================= CSR build =======================

__global__ void k_hist(const int* __restrict__ dst, int* __restrict__ cnt, int e) {
    int i = blockIdx.x * blockDim.x + threadIdx.x;
    if (i < e) atomicAdd(&cnt[dst[i]], 1);
}

__global__ void k_scan1(const int* __restrict__ cnt, int* __restrict__ rowptr,
                        int* __restrict__ blk, int n) {
    __shared__ int sdata[256];
    int b = blockIdx.x, t = threadIdx.x;
    int base = b * SCAN_BLK + t * 4;
    int v0 = 0, v1 = 0, v2 = 0, v3 = 0;
    if (base + 0 < n) v0 = cnt[base + 0];
    if (base + 1 < n) v1 = cnt[base + 1];
    if (base + 2 < n) v2 = cnt[base + 2];
    if (base + 3 < n) v3 = cnt[base + 3];
    int s = v0 + v1 + v2 + v3;
    sdata[t] = s;
    __syncthreads();
    for (int off = 1; off < 256; off <<= 1) {
        int x = (t >= off) ? sdata[t - off] : 0;
        __syncthreads();
        sdata[t] += x;
        __syncthreads();
    }
    int excl = sdata[t] - s;
    if (t == 255) blk[b] = sdata[255];
    int run = excl;
    if (base + 0 < n) { rowptr[base + 0] = run; run += v0; }
    if (base + 1 < n) { rowptr[base + 1] = run; run += v1; }
    if (base + 2 < n) { rowptr[base + 2] = run; run += v2; }
    if (base + 3 < n) { rowptr[base + 3] = run; }
}

__global__ void k_scan2(int* __restrict__ blk, int nb) {
    __shared__ int s[128];
    int t = threadIdx.x;
    int v = (t < nb) ? blk[t] : 0;
    s[t] = v;
    __syncthreads();
    for (int off = 1; off < 128; off <<= 1) {
        int x = (t >= off) ? s[t - off] : 0;
        __syncthreads();
        s[t] += x;
        __syncthreads();
    }
    if (t < nb) blk[t] = s[t] - v;
}

// scan3 + dinv + xs = dinv*x (padded stride 12)  (fused epilogue of CSR build)
__global__ void k_scan3(int* __restrict__ rowptr, const int* __restrict__ blk,
                        int* __restrict__ cursor, const int* __restrict__ cnt,
                        float* __restrict__ dinv, const float* __restrict__ x,
                        float* __restrict__ xs, int n) {
    int i = blockIdx.x * blockDim.x + threadIdx.x;
    if (i < n) {
        int r = rowptr[i] + blk[i / SCAN_BLK];
        rowptr[i] = r;
        cursor[i] = r;
        float rv = rsqrtf((float)(cnt[i] + 1));
        dinv[i] = rv;
        #pragma unroll
        for (int c = 0; c < INCH; c++)
            xs[i * XSP + c] = rv * x[i * INCH + c];
        xs[i * XSP + 10] = 0.0f;
        xs[i * XSP + 11] = 0.0f;
    }
}

__global__ void k_scatter(const int* __restrict__ src, const int* __restrict__ dst,
                          int* __restrict__ cursor, int* __restrict__ srclist, int e) {
    int i = blockIdx.x * blockDim.x + threadIdx.x;
    if (i < e) {
        int p = atomicAdd(&cursor[dst[i]], 1);
        srclist[p] = src[i];
    }
}

// W2 (k-major fp32) -> W2T (j-major fp16): W2T[j][k] = W2[k][j]
__global__ void k_w2t(const float* __restrict__ W2, __half* __restrict__ W2T, int sz) {
    int i = blockIdx.x * blockDim.x + threadIdx.x;
    if (i < sz) {
        int k = i / HID, j = i % HID;
        W2T[j * HID + k] = __float2half(W2[i]);
    }
}

// ======================= layer 1 fused: agg + GEMM1, outputs h1' = fp16(dinv*relu) ===
__global__ __launch_bounds__(256) void k_l1fused(
        const int* __restrict__ rowptr, const int* __restrict__ cnt,
        const int* __restrict__ srclist, const float* __restrict__ dinv,
        const float* __restrict__ xs, const float* __restrict__ W1,
        const float* __restrict__ b1, __half* __restrict__ h1, int n) {
    int t = blockIdx.x * blockDim.x + threadIdx.x;
    int node = t >> 5;              // 32 lanes per node
    int l32 = t & 31;
    if (node >= n) return;

    int lo = rowptr[node], deg = cnt[node];
    float acc[INCH];
    #pragma unroll
    for (int c = 0; c < INCH; c++) acc[c] = 0.0f;

    for (int e = lo + l32; e < lo + deg; e += 32) {
        int s = srclist[e];
        const float4* xr = reinterpret_cast<const float4*>(xs + (size_t)s * XSP);
        float4 v0 = xr[0];
        float4 v1 = xr[1];
        float2 v2 = *reinterpret_cast<const float2*>(xs + (size_t)s * XSP + 8);
        acc[0] += v0.x; acc[1] += v0.y; acc[2] += v0.z; acc[3] += v0.w;
        acc[4] += v1.x; acc[5] += v1.y; acc[6] += v1.z; acc[7] += v1.w;
        acc[8] += v2.x; acc[9] += v2.y;
    }
    #pragma unroll
    for (int m = 16; m; m >>= 1) {
        #pragma unroll
        for (int c = 0; c < INCH; c++)
            acc[c] += __shfl_xor(acc[c], m, 32);
    }
    float r = dinv[node];
    float agg[INCH];
    #pragma unroll
    for (int c = 0; c < INCH; c++)
        agg[c] = r * (acc[c] + xs[node * XSP + c]);

    // GEMM1: each lane computes 4 output channels; store h1' = fp16(r*relu(.))
    int j0 = l32 * 4;
    float4 o = *reinterpret_cast<const float4*>(b1 + j0);
    #pragma unroll
    for (int c = 0; c < INCH; c++) {
        const float4 wv = *reinterpret_cast<const float4*>(W1 + c * HID + j0);
        o.x = fmaf(agg[c], wv.x, o.x);
        o.y = fmaf(agg[c], wv.y, o.y);
        o.z = fmaf(agg[c], wv.z, o.z);
        o.w = fmaf(agg[c], wv.w, o.w);
    }
    __half2 p0 = __floats2half2_rn(r * fmaxf(o.x, 0.f), r * fmaxf(o.y, 0.f));
    __half2 p1 = __floats2half2_rn(r * fmaxf(o.z, 0.f), r * fmaxf(o.w, 0.f));
    uint2 pk;
    pk.x = *reinterpret_cast<unsigned int*>(&p0);
    pk.y = *reinterpret_cast<unsigned int*>(&p1);
    *reinterpret_cast<uint2*>(h1 + (size_t)node * HID + j0) = pk;
}

// ======================= layer 2 fused: gather (16 lanes/node) + MFMA GEMM ==========
// 16 nodes/block. Gather: lane owns 8 channels (uint4), fp32 accum, 8-deep unroll.
// agg -> fp16 LDS aggH[16][128]; W2T (j-major fp16) staged to LDS; 4 waves x 2 j-tiles
// of mfma_f32_16x16x32_f16 (A: row=l&15,k=(l>>4)*8+i; B: col=l&15; D: col=l&15,
// row=(l>>4)*4+reg).
__global__ __launch_bounds__(256) void k_agg2gemm2(
        const int* __restrict__ rowptr, const int* __restrict__ cnt,
        const int* __restrict__ srclist, const float* __restrict__ dinv,
        const __half* __restrict__ h1, const __half* __restrict__ W2T,
        const float* __restrict__ b2, float* __restrict__ u, int n) {
    __shared__ __half W2s[HID * HID];     // 32 KB, j-major [j][k]
    __shared__ __half aggH[16 * HID];     // 4 KB
    int t = threadIdx.x;
    for (int i = t * 8; i < HID * HID; i += 256 * 8)
        *reinterpret_cast<uint4*>(&W2s[i]) = *reinterpret_cast<const uint4*>(&W2T[i]);

    int nl = t >> 4;            // node-local 0..15
    int cl = t & 15;            // channel-lane 0..15
    int j0 = cl * 8;
    int node = blockIdx.x * 16 + nl;

    if (node < n) {
        float acc[8];
        #pragma unroll
        for (int i = 0; i < 8; i++) acc[i] = 0.0f;
        int lo = rowptr[node], hi = lo + cnt[node];
        int e = lo;
        for (; e + 8 <= hi; e += 8) {
            uint4 q[8];
            #pragma unroll
            for (int m = 0; m < 8; m++) {
                int s = srclist[e + m];
                q[m] = *reinterpret_cast<const uint4*>(h1 + (size_t)s * HID + j0);
            }
            #pragma unroll
            for (int m = 0; m < 8; m++) {
                const __half* hq = reinterpret_cast<const __half*>(&q[m]);
                #pragma unroll
                for (int i = 0; i < 8; i++) acc[i] += __half2float(hq[i]);
            }
        }
        for (; e < hi; e++) {
            int s = srclist[e];
            uint4 q = *reinterpret_cast<const uint4*>(h1 + (size_t)s * HID + j0);
            const __half* hq = reinterpret_cast<const __half*>(&q);
            #pragma unroll
            for (int i = 0; i < 8; i++) acc[i] += __half2float(hq[i]);
        }
        float r = dinv[node];
        uint4 qs = *reinterpret_cast<const uint4*>(h1 + (size_t)node * HID + j0);
        const __half* hs = reinterpret_cast<const __half*>(&qs);
        __half outv[8];
        #pragma unroll
        for (int i = 0; i < 8; i++)
            outv[i] = __float2half(r * (acc[i] + __half2float(hs[i])));
        *reinterpret_cast<uint4*>(&aggH[nl * HID + j0]) = *reinterpret_cast<uint4*>(outv);
    }
    __syncthreads();

    // MFMA phase
    using half8 = __attribute__((ext_vector_type(8))) _Float16;
    using f32x4 = __attribute__((ext_vector_type(4))) float;
    int w = t >> 6, lane = t & 63;
    int row = lane & 15;        // A row / B col / D col
    int kg = lane >> 4;         // k-group
    half8 a[4];
    #pragma unroll
    for (int kt = 0; kt < 4; kt++)
        a[kt] = *reinterpret_cast<const half8*>(&aggH[row * HID + kt * 32 + kg * 8]);
    int node0 = blockIdx.x * 16;
    #pragma unroll
    for (int p = 0; p < 2; p++) {
        int jt = w * 2 + p;
        int j = jt * 16 + row;  // B col / output col
        f32x4 c;
        float bb = b2[j];
        c[0] = bb; c[1] = bb; c[2] = bb; c[3] = bb;
        #pragma unroll
        for (int kt = 0; kt < 4; kt++) {
            half8 bfr = *reinterpret_cast<const half8*>(&W2s[j * HID + kt * 32 + kg * 8]);
            c = __builtin_amdgcn_mfma_f32_16x16x32_f16(a[kt], bfr, c, 0, 0, 0);
        }
        #pragma unroll
        for (int i = 0; i < 4; i++) {
            int nn = node0 + kg * 4 + i;     // D row = node index
            if (nn < n) u[(size_t)nn * HID + j] = fmaxf(c[i], 0.0f);
        }
    }
}

// ======================= pool + MLP =======================
__global__ void k7_pool_mlp(const float* __restrict__ h2, const int* __restrict__ batch,
                            const float* __restrict__ Wm1, const float* __restrict__ bm1,
                            const float* __restrict__ Wm2, const float* __restrict__ bm2,
                            float* __restrict__ out, int n) {
    int g = blockIdx.x;
    int j = threadIdx.x;   // 128 threads
    int a = 0, b = n;
    while (a < b) { int m = (a + b) >> 1; if (batch[m] < g) a = m + 1; else b = m; }
    int lo = a;
    b = n;
    while (a < b) { int m = (a + b) >> 1; if (batch[m] < g + 1) a = m + 1; else b = m; }
    int hi = a;

    float sum = 0.0f;
    for (int i = lo; i < hi; i++) sum += h2[(size_t)i * HID + j];
    float cnt = (float)(hi - lo);
    float gj = sum / fmaxf(cnt, 1.0f);

    __shared__ float gl[HID];
    gl[j] = gj;
    __syncthreads();

    float acc = bm1[j];
    #pragma unroll 8
    for (int k = 0; k < HID; k++) acc = fmaf(gl[k], Wm1[k * HID + j], acc);
    float y = tanhf(acc) * Wm2[j];

    __shared__ float red[HID];
    red[j] = y;
    __syncthreads();
    if (j < 64) {
        float v = red[j] + red[j + 64];
        for (int off = 32; off; off >>= 1) v += __shfl_down(v, off);
        if (j == 0) out[g] = v + bm2[0];
    }
}

extern "C" void kernel_launch(void* const* d_in, const int* in_sizes, int n_in,
                              void* d_out, int out_size, void* d_ws, size_t ws_size,
                              hipStream_t stream) {
    const float* x    = (const float*)d_in[0];
    const int*   ei   = (const int*)d_in[1];
    const int*   batch= (const int*)d_in[2];
    const float* W1   = (const float*)d_in[4];
    const float* b1   = (const float*)d_in[5];
    const float* W2   = (const float*)d_in[6];
    const float* b2   = (const float*)d_in[7];
    const float* Wm1  = (const float*)d_in[8];
    const float* bm1  = (const float*)d_in[9];
    const float* Wm2  = (const float*)d_in[10];
    const float* bm2  = (const float*)d_in[11];
    float* out = (float*)d_out;

    const int N = in_sizes[0] / INCH;       // 100000
    const int E = in_sizes[1] / 2;          // 1600000
    const int G = NGRAPH;                   // 1000
    const int NB = (N + SCAN_BLK - 1) / SCAN_BLK;   // 98 (<=128 required by k_scan2)

    char* w = (char*)d_ws;
    int*    cnt     = (int*)w;     w += (size_t)N * 4;
    int*    rowptr  = (int*)w;     w += (size_t)N * 4;
    int*    cursor  = (int*)w;     w += (size_t)N * 4;
    int*    blk     = (int*)w;     w += 256 * 4;
    float*  dinv    = (float*)w;   w += (size_t)N * 4;
    float*  xs      = (float*)w;   w += (size_t)N * XSP * 4;   // padded stride 12
    int*    srclist = (int*)w;     w += (size_t)E * 4;
    __half* h1      = (__half*)w;  w += (size_t)N * HID * 2;   // h1' fp16 (25.6 MB)
    __half* W2T     = (__half*)w;  w += (size_t)HID * HID * 2; // 32 KB fp16 W2^T (j-major)
    float*  u       = (float*)w;   w += (size_t)N * HID * 4;   // h2 output

    const int* src = ei;
    const int* dst = ei + E;

    hipMemsetAsync(cnt, 0, (size_t)N * sizeof(int), stream);

    k_hist   <<<(E + 255) / 256, 256, 0, stream>>>(dst, cnt, E);
    k_w2t    <<<(HID * HID + 255) / 256, 256, 0, stream>>>(W2, W2T, HID * HID);
    k_scan1  <<<NB, 256, 0, stream>>>(cnt, rowptr, blk, N);
    k_scan2  <<<1, 128, 0, stream>>>(blk, NB);
    k_scan3  <<<(N + 255) / 256, 256, 0, stream>>>(rowptr, blk, cursor, cnt, dinv, x, xs, N);
    k_scatter<<<(E + 255) / 256, 256, 0, stream>>>(src, dst, cursor, srclist, E);

    k_l1fused<<<(N * 32 + 255) / 256, 256, 0, stream>>>(rowptr, cnt, srclist, dinv,
                                                        xs, W1, b1, h1, N);
    k_agg2gemm2<<<(N + 15) / 16, 256, 0, stream>>>(rowptr, cnt, srclist, dinv,
                                                   h1, W2T, b2, u, N);
    k7_pool_mlp<<<G, HID, 0, stream>>>(u, batch, Wm1, bm1, Wm2, bm2, out, N);
}

// Round 18
// 411.104 us; speedup vs baseline: 9.2786x; 1.1072x over previous
//
#include <hip/hip_runtime.h>
#include <hip/hip_fp16.h>

#define INCH 10
#define XSP 12          // padded xs stride (12 floats = 48 B, 16B-aligned rows)
#define HID 128
#define NGRAPH 1000
#define SCAN_BLK 1024   // elements per scan block
#define SC_CH 1024      // edges per scatter block (4/thread)
#define SC_PASS 8       // dst-range passes
#define SC_RANGE 12500  // N / SC_PASS

// ======================= CSR build =======================

__global__ void k_hist(const int* __restrict__ dst, int* __restrict__ cnt, int e) {
    int i = blockIdx.x * blockDim.x + threadIdx.x;
    if (i < e) atomicAdd(&cnt[dst[i]], 1);
}

__global__ void k_scan1(const int* __restrict__ cnt, int* __restrict__ rowptr,
                        int* __restrict__ blk, int n) {
    __shared__ int sdata[256];
    int b = blockIdx.x, t = threadIdx.x;
    int base = b * SCAN_BLK + t * 4;
    int v0 = 0, v1 = 0, v2 = 0, v3 = 0;
    if (base + 0 < n) v0 = cnt[base + 0];
    if (base + 1 < n) v1 = cnt[base + 1];
    if (base + 2 < n) v2 = cnt[base + 2];
    if (base + 3 < n) v3 = cnt[base + 3];
    int s = v0 + v1 + v2 + v3;
    sdata[t] = s;
    __syncthreads();
    for (int off = 1; off < 256; off <<= 1) {
        int x = (t >= off) ? sdata[t - off] : 0;
        __syncthreads();
        sdata[t] += x;
        __syncthreads();
    }
    int excl = sdata[t] - s;
    if (t == 255) blk[b] = sdata[255];
    int run = excl;
    if (base + 0 < n) { rowptr[base + 0] = run; run += v0; }
    if (base + 1 < n) { rowptr[base + 1] = run; run += v1; }
    if (base + 2 < n) { rowptr[base + 2] = run; run += v2; }
    if (base + 3 < n) { rowptr[base + 3] = run; }
}

__global__ void k_scan2(int* __restrict__ blk, int nb) {
    __shared__ int s[128];
    int t = threadIdx.x;
    int v = (t < nb) ? blk[t] : 0;
    s[t] = v;
    __syncthreads();
    for (int off = 1; off < 128; off <<= 1) {
        int x = (t >= off) ? s[t - off] : 0;
        __syncthreads();
        s[t] += x;
        __syncthreads();
    }
    if (t < nb) blk[t] = s[t] - v;
}

// scan3 + dinv + xs = dinv*x (padded stride 12)  (fused epilogue of CSR build)
__global__ void k_scan3(int* __restrict__ rowptr, const int* __restrict__ blk,
                        int* __restrict__ cursor, const int* __restrict__ cnt,
                        float* __restrict__ dinv, const float* __restrict__ x,
                        float* __restrict__ xs, int n) {
    int i = blockIdx.x * blockDim.x + threadIdx.x;
    if (i < n) {
        int r = rowptr[i] + blk[i / SCAN_BLK];
        rowptr[i] = r;
        cursor[i] = r;
        float rv = rsqrtf((float)(cnt[i] + 1));
        dinv[i] = rv;
        #pragma unroll
        for (int c = 0; c < INCH; c++)
            xs[i * XSP + c] = rv * x[i * INCH + c];
        xs[i * XSP + 10] = 0.0f;
        xs[i * XSP + 11] = 0.0f;
    }
}

// pass-phased scatter: edges held in registers; pass p commits only dst-range p.
// Active srclist write window per pass ~800KB -> L2 lines fill before eviction.
__global__ void k_scatter(const int* __restrict__ src, const int* __restrict__ dst,
                          int* __restrict__ cursor, int* __restrict__ srclist, int e) {
    int base = blockIdx.x * SC_CH;
    int t = threadIdx.x;
    int se[4], de[4];
    #pragma unroll
    for (int i = 0; i < 4; i++) {
        int idx = base + i * 256 + t;
        bool v = idx < e;
        se[i] = v ? src[idx] : 0;
        de[i] = v ? dst[idx] : -1;        // -1 => guarded out below
    }
    #pragma unroll
    for (int p = 0; p < SC_PASS; p++) {
        #pragma unroll
        for (int i = 0; i < 4; i++) {
            if (de[i] >= 0 && (de[i] / SC_RANGE) == p) {
                int pos = atomicAdd(&cursor[de[i]], 1);
                srclist[pos] = se[i];
            }
        }
    }
}

// W2 (k-major fp32) -> W2T (j-major fp16): W2T[j][k] = W2[k][j]
__global__ void k_w2t(const float* __restrict__ W2, __half* __restrict__ W2T, int sz) {
    int i = blockIdx.x * blockDim.x + threadIdx.x;
    if (i < sz) {
        int k = i / HID, j = i % HID;
        W2T[j * HID + k] = __float2half(W2[i]);
    }
}

// ======================= layer 1 fused: agg + GEMM1, outputs h1' = fp16(dinv*relu) ===
__global__ __launch_bounds__(256) void k_l1fused(
        const int* __restrict__ rowptr, const int* __restrict__ cnt,
        const int* __restrict__ srclist, const float* __restrict__ dinv,
        const float* __restrict__ xs, const float* __restrict__ W1,
        const float* __restrict__ b1, __half* __restrict__ h1, int n) {
    int t = blockIdx.x * blockDim.x + threadIdx.x;
    int node = t >> 5;              // 32 lanes per node
    int l32 = t & 31;
    if (node >= n) return;

    int lo = rowptr[node], deg = cnt[node];
    float acc[INCH];
    #pragma unroll
    for (int c = 0; c < INCH; c++) acc[c] = 0.0f;

    for (int e = lo + l32; e < lo + deg; e += 32) {
        int s = srclist[e];
        const float4* xr = reinterpret_cast<const float4*>(xs + (size_t)s * XSP);
        float4 v0 = xr[0];
        float4 v1 = xr[1];
        float2 v2 = *reinterpret_cast<const float2*>(xs + (size_t)s * XSP + 8);
        acc[0] += v0.x; acc[1] += v0.y; acc[2] += v0.z; acc[3] += v0.w;
        acc[4] += v1.x; acc[5] += v1.y; acc[6] += v1.z; acc[7] += v1.w;
        acc[8] += v2.x; acc[9] += v2.y;
    }
    #pragma unroll
    for (int m = 16; m; m >>= 1) {
        #pragma unroll
        for (int c = 0; c < INCH; c++)
            acc[c] += __shfl_xor(acc[c], m, 32);
    }
    float r = dinv[node];
    float agg[INCH];
    #pragma unroll
    for (int c = 0; c < INCH; c++)
        agg[c] = r * (acc[c] + xs[node * XSP + c]);

    // GEMM1: each lane computes 4 output channels; store h1' = fp16(r*relu(.))
    int j0 = l32 * 4;
    float4 o = *reinterpret_cast<const float4*>(b1 + j0);
    #pragma unroll
    for (int c = 0; c < INCH; c++) {
        const float4 wv = *reinterpret_cast<const float4*>(W1 + c * HID + j0);
        o.x = fmaf(agg[c], wv.x, o.x);
        o.y = fmaf(agg[c], wv.y, o.y);
        o.z = fmaf(agg[c], wv.z, o.z);
        o.w = fmaf(agg[c], wv.w, o.w);
    }
    __half2 p0 = __floats2half2_rn(r * fmaxf(o.x, 0.f), r * fmaxf(o.y, 0.f));
    __half2 p1 = __floats2half2_rn(r * fmaxf(o.z, 0.f), r * fmaxf(o.w, 0.f));
    uint2 pk;
    pk.x = *reinterpret_cast<unsigned int*>(&p0);
    pk.y = *reinterpret_cast<unsigned int*>(&p1);
    *reinterpret_cast<uint2*>(h1 + (size_t)node * HID + j0) = pk;
}

// ======================= layer 2 fused: gather (16 lanes/node) + MFMA GEMM ==========
__global__ __launch_bounds__(256) void k_agg2gemm2(
        const int* __restrict__ rowptr, const int* __restrict__ cnt,
        const int* __restrict__ srclist, const float* __restrict__ dinv,
        const __half* __restrict__ h1, const __half* __restrict__ W2T,
        const float* __restrict__ b2, float* __restrict__ u, int n) {
    __shared__ __half W2s[HID * HID];     // 32 KB, j-major [j][k]
    __shared__ __half aggH[16 * HID];     // 4 KB
    int t = threadIdx.x;
    for (int i = t * 8; i < HID * HID; i += 256 * 8)
        *reinterpret_cast<uint4*>(&W2s[i]) = *reinterpret_cast<const uint4*>(&W2T[i]);

    int nl = t >> 4;            // node-local 0..15
    int cl = t & 15;            // channel-lane 0..15
    int j0 = cl * 8;
    int node = blockIdx.x * 16 + nl;

    if (node < n) {
        float acc[8];
        #pragma unroll
        for (int i = 0; i < 8; i++) acc[i] = 0.0f;
        int lo = rowptr[node], hi = lo + cnt[node];
        int e = lo;
        for (; e + 8 <= hi; e += 8) {
            uint4 q[8];
            #pragma unroll
            for (int m = 0; m < 8; m++) {
                int s = srclist[e + m];
                q[m] = *reinterpret_cast<const uint4*>(h1 + (size_t)s * HID + j0);
            }
            #pragma unroll
            for (int m = 0; m < 8; m++) {
                const __half* hq = reinterpret_cast<const __half*>(&q[m]);
                #pragma unroll
                for (int i = 0; i < 8; i++) acc[i] += __half2float(hq[i]);
            }
        }
        for (; e < hi; e++) {
            int s = srclist[e];
            uint4 q = *reinterpret_cast<const uint4*>(h1 + (size_t)s * HID + j0);
            const __half* hq = reinterpret_cast<const __half*>(&q);
            #pragma unroll
            for (int i = 0; i < 8; i++) acc[i] += __half2float(hq[i]);
        }
        float r = dinv[node];
        uint4 qs = *reinterpret_cast<const uint4*>(h1 + (size_t)node * HID + j0);
        const __half* hs = reinterpret_cast<const __half*>(&qs);
        __half outv[8];
        #pragma unroll
        for (int i = 0; i < 8; i++)
            outv[i] = __float2half(r * (acc[i] + __half2float(hs[i])));
        *reinterpret_cast<uint4*>(&aggH[nl * HID + j0]) = *reinterpret_cast<uint4*>(outv);
    }
    __syncthreads();

    // MFMA phase
    using half8 = __attribute__((ext_vector_type(8))) _Float16;
    using f32x4 = __attribute__((ext_vector_type(4))) float;
    int w = t >> 6, lane = t & 63;
    int row = lane & 15;        // A row / B col / D col
    int kg = lane >> 4;         // k-group
    half8 a[4];
    #pragma unroll
    for (int kt = 0; kt < 4; kt++)
        a[kt] = *reinterpret_cast<const half8*>(&aggH[row * HID + kt * 32 + kg * 8]);
    int node0 = blockIdx.x * 16;
    #pragma unroll
    for (int p = 0; p < 2; p++) {
        int jt = w * 2 + p;
        int j = jt * 16 + row;  // B col / output col
        f32x4 c;
        float bb = b2[j];
        c[0] = bb; c[1] = bb; c[2] = bb; c[3] = bb;
        #pragma unroll
        for (int kt = 0; kt < 4; kt++) {
            half8 bfr = *reinterpret_cast<const half8*>(&W2s[j * HID + kt * 32 + kg * 8]);
            c = __builtin_amdgcn_mfma_f32_16x16x32_f16(a[kt], bfr, c, 0, 0, 0);
        }
        #pragma unroll
        for (int i = 0; i < 4; i++) {
            int nn = node0 + kg * 4 + i;     // D row = node index
            if (nn < n) u[(size_t)nn * HID + j] = fmaxf(c[i], 0.0f);
        }
    }
}

// ======================= pool + MLP =======================
__global__ void k7_pool_mlp(const float* __restrict__ h2, const int* __restrict__ batch,
                            const float* __restrict__ Wm1, const float* __restrict__ bm1,
                            const float* __restrict__ Wm2, const float* __restrict__ bm2,
                            float* __restrict__ out, int n) {
    int g = blockIdx.x;
    int j = threadIdx.x;   // 128 threads
    int a = 0, b = n;
    while (a < b) { int m = (a + b) >> 1; if (batch[m] < g) a = m + 1; else b = m; }
    int lo = a;
    b = n;
    while (a < b) { int m = (a + b) >> 1; if (batch[m] < g + 1) a = m + 1; else b = m; }
    int hi = a;

    float sum = 0.0f;
    for (int i = lo; i < hi; i++) sum += h2[(size_t)i * HID + j];
    float cnt = (float)(hi - lo);
    float gj = sum / fmaxf(cnt, 1.0f);

    __shared__ float gl[HID];
    gl[j] = gj;
    __syncthreads();

    float acc = bm1[j];
    #pragma unroll 8
    for (int k = 0; k < HID; k++) acc = fmaf(gl[k], Wm1[k * HID + j], acc);
    float y = tanhf(acc) * Wm2[j];

    __shared__ float red[HID];
    red[j] = y;
    __syncthreads();
    if (j < 64) {
        float v = red[j] + red[j + 64];
        for (int off = 32; off; off >>= 1) v += __shfl_down(v, off);
        if (j == 0) out[g] = v + bm2[0];
    }
}

extern "C" void kernel_launch(void* const* d_in, const int* in_sizes, int n_in,
                              void* d_out, int out_size, void* d_ws, size_t ws_size,
                              hipStream_t stream) {
    const float* x    = (const float*)d_in[0];
    const int*   ei   = (const int*)d_in[1];
    const int*   batch= (const int*)d_in[2];
    const float* W1   = (const float*)d_in[4];
    const float* b1   = (const float*)d_in[5];
    const float* W2   = (const float*)d_in[6];
    const float* b2   = (const float*)d_in[7];
    const float* Wm1  = (const float*)d_in[8];
    const float* bm1  = (const float*)d_in[9];
    const float* Wm2  = (const float*)d_in[10];
    const float* bm2  = (const float*)d_in[11];
    float* out = (float*)d_out;

    const int N = in_sizes[0] / INCH;       // 100000
    const int E = in_sizes[1] / 2;          // 1600000
    const int G = NGRAPH;                   // 1000
    const int NB = (N + SCAN_BLK - 1) / SCAN_BLK;   // 98 (<=128 required by k_scan2)

    char* w = (char*)d_ws;
    int*    cnt     = (int*)w;     w += (size_t)N * 4;
    int*    rowptr  = (int*)w;     w += (size_t)N * 4;
    int*    cursor  = (int*)w;     w += (size_t)N * 4;
    int*    blk     = (int*)w;     w += 256 * 4;
    float*  dinv    = (float*)w;   w += (size_t)N * 4;
    float*  xs      = (float*)w;   w += (size_t)N * XSP * 4;   // padded stride 12
    int*    srclist = (int*)w;     w += (size_t)E * 4;
    __half* h1      = (__half*)w;  w += (size_t)N * HID * 2;   // h1' fp16 (25.6 MB)
    __half* W2T     = (__half*)w;  w += (size_t)HID * HID * 2; // 32 KB fp16 W2^T (j-major)
    float*  u       = (float*)w;   w += (size_t)N * HID * 4;   // h2 output

    const int* src = ei;
    const int* dst = ei + E;

    hipMemsetAsync(cnt, 0, (size_t)N * sizeof(int), stream);

    k_hist   <<<(E + 255) / 256, 256, 0, stream>>>(dst, cnt, E);
    k_w2t    <<<(HID * HID + 255) / 256, 256, 0, stream>>>(W2, W2T, HID * HID);
    k_scan1  <<<NB, 256, 0, stream>>>(cnt, rowptr, blk, N);
    k_scan2  <<<1, 128, 0, stream>>>(blk, NB);
    k_scan3  <<<(N + 255) / 256, 256, 0, stream>>>(rowptr, blk, cursor, cnt, dinv, x, xs, N);
    k_scatter<<<(E + SC_CH - 1) / SC_CH, 256, 0, stream>>>(src, dst, cursor, srclist, E);

    k_l1fused<<<(N * 32 + 255) / 256, 256, 0, stream>>>(rowptr, cnt, srclist, dinv,
                                                        xs, W1, b1, h1, N);
    k_agg2gemm2<<<(N + 15) / 16, 256, 0, stream>>>(rowptr, cnt, srclist, dinv,
                                                   h1, W2T, b2, u, N);
    k7_pool_mlp<<<G, HID, 0, stream>>>(u, batch, Wm1, bm1, Wm2, bm2, out, N);
}